// Round 2
// baseline (1344.278 us; speedup 1.0000x reference)
//
#include <hip/hip_runtime.h>

#define NNODES 50000
#define NEDGES 1600000
#define FEAT 128
#define NEG_SLOPE 0.2f

// ---------------- CSR build ----------------
// NOTE: harness passes integer inputs as int32 (edge_index: [2,E] int32).

__global__ void k_count(const int* __restrict__ ei, int* __restrict__ count) {
    int e = blockIdx.x * blockDim.x + threadIdx.x;
    if (e < NEDGES) {
        int d = ei[NEDGES + e];
        atomicAdd(&count[d], 1);
    }
}

// single-block scan: row_ptr[i] = sum_{j<i} (count[j]+1)  (+1 = self-loop)
__global__ __launch_bounds__(1024) void k_scan(const int* __restrict__ count,
                                               int* __restrict__ row_ptr) {
    __shared__ int sums[1024];
    const int per = (NNODES + 1023) / 1024;   // 49
    int tid = threadIdx.x;
    int base = tid * per;
    int local = 0;
    for (int i = 0; i < per; i++) {
        int idx = base + i;
        if (idx < NNODES) local += count[idx] + 1;
    }
    sums[tid] = local;
    __syncthreads();
    for (int off = 1; off < 1024; off <<= 1) {
        int v = 0;
        if (tid >= off) v = sums[tid - off];
        __syncthreads();
        sums[tid] += v;
        __syncthreads();
    }
    int run = sums[tid] - local;              // exclusive prefix
    for (int i = 0; i < per; i++) {
        int idx = base + i;
        if (idx < NNODES) { row_ptr[idx] = run; run += count[idx] + 1; }
    }
    if (tid == 1023) row_ptr[NNODES] = sums[1023];
}

// self-loop goes in slot 0 of each segment; fill starts at 1
__global__ void k_selfloop(const int* __restrict__ row_ptr, int* __restrict__ csr_src,
                           int* __restrict__ fill) {
    int i = blockIdx.x * blockDim.x + threadIdx.x;
    if (i < NNODES) { csr_src[row_ptr[i]] = i; fill[i] = 1; }
}

__global__ void k_scatter(const int* __restrict__ ei, const int* __restrict__ row_ptr,
                          int* __restrict__ fill, int* __restrict__ csr_src) {
    int e = blockIdx.x * blockDim.x + threadIdx.x;
    if (e < NEDGES) {
        int s = ei[e];
        int d = ei[NEDGES + e];
        int pos = atomicAdd(&fill[d], 1);
        csr_src[row_ptr[d] + pos] = s;
    }
}

// ---------------- per-layer kernels ----------------

// h = X @ W   (X: [nrows,128], W: [128,128] row-major, h: [nrows,128])
// block: 256 thr; blockIdx.y picks 64-col half; 16 rows per iter, 4 rows/thread.
__global__ __launch_bounds__(256) void k_gemm(const float* __restrict__ X,
                                              const float* __restrict__ W,
                                              float* __restrict__ Hout, int nrows) {
    __shared__ float Ws[128 * 64];   // 32 KB
    __shared__ float Xs[16 * 128];   // 8 KB
    int c0  = blockIdx.y * 64;
    int col = threadIdx.x & 63;
    int grp = threadIdx.x >> 6;      // 0..3, == wave id
    for (int i = threadIdx.x; i < 128 * 64; i += 256) {
        int k = i >> 6, c = i & 63;
        Ws[i] = W[k * 128 + c0 + c];
    }
    for (int r0 = blockIdx.x * 16; r0 < nrows; r0 += gridDim.x * 16) {
        int nr = min(16, nrows - r0);
        __syncthreads();
        for (int i = threadIdx.x; i < nr * 128; i += 256)
            Xs[i] = X[(size_t)r0 * 128 + i];
        __syncthreads();
        int rb = grp * 4;
        float a0 = 0.f, a1 = 0.f, a2 = 0.f, a3 = 0.f;
        for (int k = 0; k < 128; k++) {
            float w = Ws[k * 64 + col];          // conflict-free (2 lanes/bank)
            a0 += Xs[(rb + 0) * 128 + k] * w;    // wave-uniform -> LDS broadcast
            a1 += Xs[(rb + 1) * 128 + k] * w;
            a2 += Xs[(rb + 2) * 128 + k] * w;
            a3 += Xs[(rb + 3) * 128 + k] * w;
        }
        if (rb + 0 < nr) Hout[(size_t)(r0 + rb + 0) * 128 + c0 + col] = a0;
        if (rb + 1 < nr) Hout[(size_t)(r0 + rb + 1) * 128 + c0 + col] = a1;
        if (rb + 2 < nr) Hout[(size_t)(r0 + rb + 2) * 128 + c0 + col] = a2;
        if (rb + 3 < nr) Hout[(size_t)(r0 + rb + 3) * 128 + c0 + col] = a3;
    }
}

// e_src[n,h] = sum_c h[n,h,c]*a_src[h,c]; one wave per row, 2 ch/lane.
__global__ __launch_bounds__(256) void k_attn(const float* __restrict__ h,
                                              const float* __restrict__ a_src,
                                              const float* __restrict__ a_dst,
                                              float* __restrict__ e_src,
                                              float* __restrict__ e_dst) {
    int lane = threadIdx.x & 63;
    int wv   = threadIdx.x >> 6;
    int n    = blockIdx.x * 4 + wv;
    if (n >= NNODES) return;
    int head = lane >> 5;
    float2 hv = *(const float2*)(h + (size_t)n * 128 + lane * 2);
    float2 as = *(const float2*)(a_src + lane * 2);
    float2 ad = *(const float2*)(a_dst + lane * 2);
    float vs = hv.x * as.x + hv.y * as.y;
    float vd = hv.x * ad.x + hv.y * ad.y;
    #pragma unroll
    for (int m = 1; m <= 16; m <<= 1) {   // reduce within 32-lane half
        vs += __shfl_xor(vs, m);
        vd += __shfl_xor(vd, m);
    }
    if ((lane & 31) == 0) {
        e_src[n * 2 + head] = vs;
        e_dst[n * 2 + head] = vd;
    }
}

// one wave per dst node; lane owns channels 2L,2L+1 (head = L>=32).
// out[d] = (sum_e p_e * h[src_e]) / (sum_e p_e) + b;  p = exp(leakyrelu(es+ed))
// (softmax max-subtraction dropped: e is O(10), exp stays in fp32 range, and
//  self-loop guarantees the denom >= exp(leakyrelu(2*e_self)) > 0)
__global__ __launch_bounds__(256) void k_aggregate(const float* __restrict__ h,
                                                   const float* __restrict__ e_src,
                                                   const float* __restrict__ e_dst,
                                                   const int* __restrict__ row_ptr,
                                                   const int* __restrict__ csr_src,
                                                   const float* __restrict__ bias,
                                                   float* __restrict__ out, int relu_flag) {
    int lane = threadIdx.x & 63;
    int wv   = threadIdx.x >> 6;
    int d    = blockIdx.x * 4 + wv;
    if (d >= NNODES) return;
    int head = lane >> 5;
    float ed  = e_dst[d * 2 + head];
    int beg = row_ptr[d], end = row_ptr[d + 1];
    float accx = 0.f, accy = 0.f, ssum = 0.f;
    for (int j = beg; j < end; j++) {
        int s = csr_src[j];
        float t = e_src[s * 2 + head] + ed;
        t = t > 0.f ? t : NEG_SLOPE * t;
        float p = __expf(t);
        float2 hv = *(const float2*)(h + (size_t)s * 128 + lane * 2);
        accx += p * hv.x;
        accy += p * hv.y;
        ssum += p;     // identical across the 32 lanes of this head
    }
    float inv = 1.0f / ssum;
    float o0 = accx * inv + bias[lane * 2];
    float o1 = accy * inv + bias[lane * 2 + 1];
    if (relu_flag) { o0 = o0 > 0.f ? o0 : 0.f; o1 = o1 > 0.f ? o1 : 0.f; }
    *(float2*)(out + (size_t)d * 128 + lane * 2) = make_float2(o0, o1);
}

// ---------------- host ----------------

extern "C" void kernel_launch(void* const* d_in, const int* in_sizes, int n_in,
                              void* d_out, int out_size, void* d_ws, size_t ws_size,
                              hipStream_t stream) {
    const float* x  = (const float*)d_in[0];
    const int*   ei = (const int*)d_in[1];   // int32! harness converts int64 -> int32

    char* ws = (char*)d_ws;
    size_t off = 0;
    auto alloc = [&](size_t bytes) {
        void* p = ws + off;
        off = (off + bytes + 255) & ~(size_t)255;
        return p;
    };
    int*   count   = (int*)alloc((size_t)NNODES * 4);          // reused as fill
    int*   row_ptr = (int*)alloc((size_t)(NNODES + 1) * 4);
    int*   csr     = (int*)alloc((size_t)(NEDGES + NNODES) * 4);
    float* hbuf    = (float*)alloc((size_t)NNODES * FEAT * 4);
    float* es      = (float*)alloc((size_t)NNODES * 2 * 4);
    float* edv     = (float*)alloc((size_t)NNODES * 2 * 4);
    (void)ws_size; (void)in_sizes; (void)n_in;

    // activation ping buffer: d_out doubles as the intermediate-activation
    // buffer (aggregate writes it only after the gemm that read it completed;
    // final layer's aggregate deposits the real output there last).
    float* act = (float*)d_out;

    // CSR build (edge_index identical every call, but no cross-call state allowed)
    hipMemsetAsync(count, 0, (size_t)NNODES * 4, stream);
    k_count   <<<(NEDGES + 255) / 256, 256, 0, stream>>>(ei, count);
    k_scan    <<<1, 1024, 0, stream>>>(count, row_ptr);
    k_selfloop<<<(NNODES + 255) / 256, 256, 0, stream>>>(row_ptr, csr, count);
    k_scatter <<<(NEDGES + 255) / 256, 256, 0, stream>>>(ei, row_ptr, count, csr);

    const float* W_h = (const float*)d_in[6];
    const float* ash = (const float*)d_in[7];
    const float* adh = (const float*)d_in[8];
    const float* bh  = (const float*)d_in[9];

    struct Layer { const float *W, *as, *ad, *b; };
    Layer L[4] = {
        { (const float*)d_in[2],  (const float*)d_in[3],  (const float*)d_in[4],  (const float*)d_in[5]  },
        { W_h,              ash,        adh,        bh        },
        { W_h + 128 * 128,  ash + 128,  adh + 128,  bh + 128  },
        { (const float*)d_in[10], (const float*)d_in[11], (const float*)d_in[12], (const float*)d_in[13] },
    };

    const float* xin = x;
    for (int l = 0; l < 4; l++) {
        k_gemm<<<dim3(256, 2), 256, 0, stream>>>(xin, L[l].W, hbuf, NNODES);
        k_attn<<<(NNODES + 3) / 4, 256, 0, stream>>>(hbuf, L[l].as, L[l].ad, es, edv);
        k_aggregate<<<(NNODES + 3) / 4, 256, 0, stream>>>(hbuf, es, edv, row_ptr, csr,
                                                          L[l].b, act, l < 3 ? 1 : 0);
        xin = act;
    }
}

// Round 3
// 1126.710 us; speedup vs baseline: 1.1931x; 1.1931x over previous
//
#include <hip/hip_runtime.h>

#define NNODES 50000
#define NEDGES 1600000
#define FEAT 128
#define NEG_SLOPE 0.2f

// ---------------- CSR build ----------------
// harness passes integer inputs as int32 (edge_index: [2,E] int32).

__global__ void k_count(const int* __restrict__ ei, int* __restrict__ count) {
    int e = blockIdx.x * blockDim.x + threadIdx.x;
    if (e < NEDGES) atomicAdd(&count[ei[NEDGES + e]], 1);
}

__global__ __launch_bounds__(1024) void k_scan(const int* __restrict__ count,
                                               int* __restrict__ row_ptr) {
    __shared__ int sums[1024];
    const int per = (NNODES + 1023) / 1024;
    int tid = threadIdx.x;
    int base = tid * per;
    int local = 0;
    for (int i = 0; i < per; i++) {
        int idx = base + i;
        if (idx < NNODES) local += count[idx] + 1;   // +1 = self loop
    }
    sums[tid] = local;
    __syncthreads();
    for (int off = 1; off < 1024; off <<= 1) {
        int v = 0;
        if (tid >= off) v = sums[tid - off];
        __syncthreads();
        sums[tid] += v;
        __syncthreads();
    }
    int run = sums[tid] - local;
    for (int i = 0; i < per; i++) {
        int idx = base + i;
        if (idx < NNODES) { row_ptr[idx] = run; run += count[idx] + 1; }
    }
    if (tid == 1023) row_ptr[NNODES] = sums[1023];
}

__global__ void k_selfloop(const int* __restrict__ row_ptr, int* __restrict__ csr_src,
                           int* __restrict__ fill) {
    int i = blockIdx.x * blockDim.x + threadIdx.x;
    if (i < NNODES) { csr_src[row_ptr[i]] = i; fill[i] = 1; }
}

__global__ void k_scatter(const int* __restrict__ ei, const int* __restrict__ row_ptr,
                          int* __restrict__ fill, int* __restrict__ csr_src) {
    int e = blockIdx.x * blockDim.x + threadIdx.x;
    if (e < NEDGES) {
        int s = ei[e];
        int d = ei[NEDGES + e];
        int pos = atomicAdd(&fill[d], 1);
        csr_src[row_ptr[d] + pos] = s;
    }
}

// ---------------- fused GEMM + attention coefficients ----------------
// h = X @ W, plus e_src/e_dst epilogue. blockIdx.y picks the 64-col half,
// which is exactly one head (head0 = ch 0..63, head1 = ch 64..127), so the
// per-row attention dot reduces fully within each wave. 50000 % 16 == 0.
__global__ __launch_bounds__(256) void k_gemm_attn(const float* __restrict__ X,
                                                   const float* __restrict__ W,
                                                   const float* __restrict__ a_src,
                                                   const float* __restrict__ a_dst,
                                                   float* __restrict__ Hout,
                                                   float* __restrict__ e_src,
                                                   float* __restrict__ e_dst,
                                                   int nrows) {
    __shared__ float Ws[128 * 64];   // 32 KB
    __shared__ float Xs[16 * 128];   // 8 KB
    int head = blockIdx.y;
    int c0   = head * 64;
    int col  = threadIdx.x & 63;
    int grp  = threadIdx.x >> 6;     // wave id 0..3
    float asv = a_src[c0 + col];     // a_src is [H,C] flat = [128]
    float adv = a_dst[c0 + col];
    for (int i = threadIdx.x; i < 128 * 64; i += 256) {
        int k = i >> 6, c = i & 63;
        Ws[i] = W[k * 128 + c0 + c];
    }
    for (int r0 = blockIdx.x * 16; r0 < nrows; r0 += gridDim.x * 16) {
        __syncthreads();
        for (int i = threadIdx.x; i < 16 * 128; i += 256)
            Xs[i] = X[(size_t)r0 * 128 + i];
        __syncthreads();
        int rb = grp * 4;
        float a0 = 0.f, a1 = 0.f, a2 = 0.f, a3 = 0.f;
        for (int k = 0; k < 128; k++) {
            float w = Ws[k * 64 + col];          // 2 lanes/bank: free
            a0 += Xs[(rb + 0) * 128 + k] * w;    // wave-uniform -> broadcast
            a1 += Xs[(rb + 1) * 128 + k] * w;
            a2 += Xs[(rb + 2) * 128 + k] * w;
            a3 += Xs[(rb + 3) * 128 + k] * w;
        }
        size_t rr = (size_t)(r0 + rb);
        Hout[(rr + 0) * 128 + c0 + col] = a0;
        Hout[(rr + 1) * 128 + c0 + col] = a1;
        Hout[(rr + 2) * 128 + c0 + col] = a2;
        Hout[(rr + 3) * 128 + c0 + col] = a3;
        // attention-coefficient epilogue: per-row dot with a_src/a_dst
        float s0 = a0 * asv, s1 = a1 * asv, s2 = a2 * asv, s3 = a3 * asv;
        float d0 = a0 * adv, d1 = a1 * adv, d2 = a2 * adv, d3 = a3 * adv;
        #pragma unroll
        for (int m = 1; m < 64; m <<= 1) {
            s0 += __shfl_xor(s0, m); s1 += __shfl_xor(s1, m);
            s2 += __shfl_xor(s2, m); s3 += __shfl_xor(s3, m);
            d0 += __shfl_xor(d0, m); d1 += __shfl_xor(d1, m);
            d2 += __shfl_xor(d2, m); d3 += __shfl_xor(d3, m);
        }
        if (col == 0) {
            e_src[(rr + 0) * 2 + head] = s0; e_dst[(rr + 0) * 2 + head] = d0;
            e_src[(rr + 1) * 2 + head] = s1; e_dst[(rr + 1) * 2 + head] = d1;
            e_src[(rr + 2) * 2 + head] = s2; e_dst[(rr + 2) * 2 + head] = d2;
            e_src[(rr + 3) * 2 + head] = s3; e_dst[(rr + 3) * 2 + head] = d3;
        }
    }
}

// ---------------- aggregation ----------------
// one wave per dst; lane owns channels 2L,2L+1 (head = L>=32).
// 8-wide edge unroll: 8 independent 512B h-row gathers in flight per wave.
__global__ __launch_bounds__(256) void k_aggregate(const float* __restrict__ h,
                                                   const float* __restrict__ e_src,
                                                   const float* __restrict__ e_dst,
                                                   const int* __restrict__ row_ptr,
                                                   const int* __restrict__ csr_src,
                                                   const float* __restrict__ bias,
                                                   float* __restrict__ out, int relu_flag) {
    int lane = threadIdx.x & 63;
    int wv   = threadIdx.x >> 6;
    int d    = blockIdx.x * 4 + wv;
    if (d >= NNODES) return;
    int head = lane >> 5;
    float ed = e_dst[d * 2 + head];
    int beg = row_ptr[d], end = row_ptr[d + 1];
    float accx = 0.f, accy = 0.f, ssum = 0.f;
    int j = beg;
    for (; j + 8 <= end; j += 8) {
        int s0 = csr_src[j+0], s1 = csr_src[j+1], s2 = csr_src[j+2], s3 = csr_src[j+3];
        int s4 = csr_src[j+4], s5 = csr_src[j+5], s6 = csr_src[j+6], s7 = csr_src[j+7];
        float2 h0 = *(const float2*)(h + (size_t)s0 * 128 + lane * 2);
        float2 h1 = *(const float2*)(h + (size_t)s1 * 128 + lane * 2);
        float2 h2 = *(const float2*)(h + (size_t)s2 * 128 + lane * 2);
        float2 h3 = *(const float2*)(h + (size_t)s3 * 128 + lane * 2);
        float2 h4 = *(const float2*)(h + (size_t)s4 * 128 + lane * 2);
        float2 h5 = *(const float2*)(h + (size_t)s5 * 128 + lane * 2);
        float2 h6 = *(const float2*)(h + (size_t)s6 * 128 + lane * 2);
        float2 h7 = *(const float2*)(h + (size_t)s7 * 128 + lane * 2);
        float t0 = e_src[s0*2+head] + ed, t1 = e_src[s1*2+head] + ed;
        float t2 = e_src[s2*2+head] + ed, t3 = e_src[s3*2+head] + ed;
        float t4 = e_src[s4*2+head] + ed, t5 = e_src[s5*2+head] + ed;
        float t6 = e_src[s6*2+head] + ed, t7 = e_src[s7*2+head] + ed;
        t0 = t0 > 0.f ? t0 : NEG_SLOPE * t0;  t1 = t1 > 0.f ? t1 : NEG_SLOPE * t1;
        t2 = t2 > 0.f ? t2 : NEG_SLOPE * t2;  t3 = t3 > 0.f ? t3 : NEG_SLOPE * t3;
        t4 = t4 > 0.f ? t4 : NEG_SLOPE * t4;  t5 = t5 > 0.f ? t5 : NEG_SLOPE * t5;
        t6 = t6 > 0.f ? t6 : NEG_SLOPE * t6;  t7 = t7 > 0.f ? t7 : NEG_SLOPE * t7;
        float p0 = __expf(t0), p1 = __expf(t1), p2 = __expf(t2), p3 = __expf(t3);
        float p4 = __expf(t4), p5 = __expf(t5), p6 = __expf(t6), p7 = __expf(t7);
        accx += p0*h0.x + p1*h1.x + p2*h2.x + p3*h3.x
              + p4*h4.x + p5*h5.x + p6*h6.x + p7*h7.x;
        accy += p0*h0.y + p1*h1.y + p2*h2.y + p3*h3.y
              + p4*h4.y + p5*h5.y + p6*h6.y + p7*h7.y;
        ssum += p0+p1+p2+p3+p4+p5+p6+p7;
    }
    for (; j < end; j++) {
        int s = csr_src[j];
        float t = e_src[s*2+head] + ed;
        t = t > 0.f ? t : NEG_SLOPE * t;
        float p = __expf(t);
        float2 hv = *(const float2*)(h + (size_t)s * 128 + lane * 2);
        accx += p * hv.x; accy += p * hv.y; ssum += p;
    }
    float inv = 1.0f / ssum;
    float o0 = accx * inv + bias[lane * 2];
    float o1 = accy * inv + bias[lane * 2 + 1];
    if (relu_flag) { o0 = fmaxf(o0, 0.f); o1 = fmaxf(o1, 0.f); }
    *(float2*)(out + (size_t)d * 128 + lane * 2) = make_float2(o0, o1);
}

// ---------------- host ----------------

extern "C" void kernel_launch(void* const* d_in, const int* in_sizes, int n_in,
                              void* d_out, int out_size, void* d_ws, size_t ws_size,
                              hipStream_t stream) {
    const float* x  = (const float*)d_in[0];
    const int*   ei = (const int*)d_in[1];   // int32 (harness converts int64)

    char* ws = (char*)d_ws;
    size_t off = 0;
    auto alloc = [&](size_t bytes) {
        void* p = ws + off;
        off = (off + bytes + 255) & ~(size_t)255;
        return p;
    };
    int*   count   = (int*)alloc((size_t)NNODES * 4);          // reused as fill
    int*   row_ptr = (int*)alloc((size_t)(NNODES + 1) * 4);
    int*   csr     = (int*)alloc((size_t)(NEDGES + NNODES) * 4);
    float* hbuf    = (float*)alloc((size_t)NNODES * FEAT * 4);
    float* es      = (float*)alloc((size_t)NNODES * 2 * 4);
    float* edv     = (float*)alloc((size_t)NNODES * 2 * 4);
    (void)ws_size; (void)in_sizes; (void)n_in;

    float* act = (float*)d_out;   // ping buffer; final layer lands real output

    hipMemsetAsync(count, 0, (size_t)NNODES * 4, stream);
    k_count   <<<(NEDGES + 255) / 256, 256, 0, stream>>>(ei, count);
    k_scan    <<<1, 1024, 0, stream>>>(count, row_ptr);
    k_selfloop<<<(NNODES + 255) / 256, 256, 0, stream>>>(row_ptr, csr, count);
    k_scatter <<<(NEDGES + 255) / 256, 256, 0, stream>>>(ei, row_ptr, count, csr);

    const float* W_h = (const float*)d_in[6];
    const float* ash = (const float*)d_in[7];
    const float* adh = (const float*)d_in[8];
    const float* bh  = (const float*)d_in[9];

    struct Layer { const float *W, *as, *ad, *b; };
    Layer L[4] = {
        { (const float*)d_in[2],  (const float*)d_in[3],  (const float*)d_in[4],  (const float*)d_in[5]  },
        { W_h,              ash,        adh,        bh        },
        { W_h + 128 * 128,  ash + 128,  adh + 128,  bh + 128  },
        { (const float*)d_in[10], (const float*)d_in[11], (const float*)d_in[12], (const float*)d_in[13] },
    };

    const float* xin = x;
    for (int l = 0; l < 4; l++) {
        k_gemm_attn<<<dim3(256, 2), 256, 0, stream>>>(xin, L[l].W, L[l].as, L[l].ad,
                                                      hbuf, es, edv, NNODES);
        k_aggregate<<<(NNODES + 3) / 4, 256, 0, stream>>>(hbuf, es, edv, row_ptr, csr,
                                                          L[l].b, act, l < 3 ? 1 : 0);
        xin = act;
    }
}

// Round 4
// 874.119 us; speedup vs baseline: 1.5379x; 1.2890x over previous
//
#include <hip/hip_runtime.h>

#define NNODES 50000
#define NEDGES 1600000
#define NEG_SLOPE 0.2f

typedef __attribute__((ext_vector_type(8))) short short8;
typedef __attribute__((ext_vector_type(4))) float f32x4;

static __device__ __forceinline__ unsigned short f2bf(float f) {
    unsigned u = __float_as_uint(f);
    unsigned r = u + 0x7FFFu + ((u >> 16) & 1u);   // RNE
    return (unsigned short)(r >> 16);
}
static __device__ __forceinline__ float bf2f(unsigned short h) {
    return __uint_as_float(((unsigned)h) << 16);
}

// ---------------- CSR build (edge_index arrives as int32) ----------------

__global__ void k_count(const int* __restrict__ ei, int* __restrict__ count) {
    int e = blockIdx.x * blockDim.x + threadIdx.x;
    if (e < NEDGES) atomicAdd(&count[ei[NEDGES + e]], 1);
}

__global__ __launch_bounds__(1024) void k_scan(const int* __restrict__ count,
                                               int* __restrict__ row_ptr) {
    __shared__ int sums[1024];
    const int per = (NNODES + 1023) / 1024;
    int tid = threadIdx.x;
    int base = tid * per;
    int local = 0;
    for (int i = 0; i < per; i++) {
        int idx = base + i;
        if (idx < NNODES) local += count[idx] + 1;   // +1 = self loop
    }
    sums[tid] = local;
    __syncthreads();
    for (int off = 1; off < 1024; off <<= 1) {
        int v = 0;
        if (tid >= off) v = sums[tid - off];
        __syncthreads();
        sums[tid] += v;
        __syncthreads();
    }
    int run = sums[tid] - local;
    for (int i = 0; i < per; i++) {
        int idx = base + i;
        if (idx < NNODES) { row_ptr[idx] = run; run += count[idx] + 1; }
    }
    if (tid == 1023) row_ptr[NNODES] = sums[1023];
}

__global__ void k_selfloop(const int* __restrict__ row_ptr, int* __restrict__ csr_src,
                           int* __restrict__ fill) {
    int i = blockIdx.x * blockDim.x + threadIdx.x;
    if (i < NNODES) { csr_src[row_ptr[i]] = i; fill[i] = 1; }
}

__global__ void k_scatter(const int* __restrict__ ei, const int* __restrict__ row_ptr,
                          int* __restrict__ fill, int* __restrict__ csr_src) {
    int e = blockIdx.x * blockDim.x + threadIdx.x;
    if (e < NEDGES) {
        int s = ei[e];
        int d = ei[NEDGES + e];
        int pos = atomicAdd(&fill[d], 1);
        csr_src[row_ptr[d] + pos] = s;
    }
}

// ---------------- layer-0 input split: x -> bf16 hi/lo planes ----------------

__global__ void k_split(const float* __restrict__ x, unsigned short* __restrict__ hi,
                        unsigned short* __restrict__ lo) {
    int i = blockIdx.x * blockDim.x + threadIdx.x;   // one float4 per thread
    if (i >= NNODES * 128 / 4) return;
    float4 v = *(const float4*)(x + (size_t)i * 4);
    unsigned short h0 = f2bf(v.x), h1 = f2bf(v.y), h2 = f2bf(v.z), h3 = f2bf(v.w);
    ushort4 hv = make_ushort4(h0, h1, h2, h3);
    ushort4 lv = make_ushort4(f2bf(v.x - bf2f(h0)), f2bf(v.y - bf2f(h1)),
                              f2bf(v.z - bf2f(h2)), f2bf(v.w - bf2f(h3)));
    *(ushort4*)(hi + (size_t)i * 4) = hv;
    *(ushort4*)(lo + (size_t)i * 4) = lv;
}

// ---------------- MFMA GEMM + attention-coefficient epilogue ----------------
// C = X*W via split-bf16: Xh*Wh + Xh*Wl + Xl*Wh (err ~2^-17 rel).
// Block = 128 rows x 128 cols x K=128. 4 waves; wave w owns cols [w*32,w*32+32).
// W frags in registers (loaded once); A hi/lo in LDS, 16B chunks XOR-swizzled.
__global__ __launch_bounds__(256, 2) void k_gemm_mfma(
        const unsigned short* __restrict__ Ahi, const unsigned short* __restrict__ Alo,
        const float* __restrict__ W,
        const float* __restrict__ a_src, const float* __restrict__ a_dst,
        float* __restrict__ Hout, float* __restrict__ e_src, float* __restrict__ e_dst)
{
    __shared__ __align__(16) short sAhi[128 * 128];   // 32 KB
    __shared__ __align__(16) short sAlo[128 * 128];   // 32 KB
    __shared__ float eS[4][128];                      // 2 KB
    __shared__ float eD[4][128];                      // 2 KB

    const int tid  = threadIdx.x;
    const int lane = tid & 63;
    const int w    = tid >> 6;     // wave 0..3
    const int l15  = lane & 15;
    const int quad = lane >> 4;    // 0..3
    const int row0 = blockIdx.x * 128;

    // ---- B (W) fragments: hi/lo bf16, kept in registers ----
    // B-operand layout: lane holds B[k=quad*8+j][n=lane&15] for the K=32 window.
    short8 Bh[2][4], Bl[2][4];
    for (int nt = 0; nt < 2; nt++) {
        int n = w * 32 + nt * 16 + l15;
        for (int ks = 0; ks < 4; ks++) {
            short8 bh, bl;
            #pragma unroll
            for (int j = 0; j < 8; j++) {
                float wv = W[(size_t)(ks * 32 + quad * 8 + j) * 128 + n];
                unsigned short h = f2bf(wv);
                bh[j] = (short)h;
                bl[j] = (short)f2bf(wv - bf2f(h));
            }
            Bh[nt][ks] = bh; Bl[nt][ks] = bl;
        }
    }

    // ---- stage A hi/lo into LDS; chunk column cp = kc ^ (m&15) (bank-free) ----
    for (int i = tid; i < 2048; i += 256) {     // 2048 16B-chunks per plane
        int m  = i >> 4;                        // row 0..127
        int kc = i & 15;                        // 16B chunk within row
        int g  = row0 + m; if (g > NNODES - 1) g = NNODES - 1;   // tail clamp
        int cp = kc ^ (m & 15);
        short8 vh = *(const short8*)(Ahi + (size_t)g * 128 + kc * 8);
        short8 vl = *(const short8*)(Alo + (size_t)g * 128 + kc * 8);
        *(short8*)&sAhi[m * 128 + cp * 8] = vh;
        *(short8*)&sAlo[m * 128 + cp * 8] = vl;
    }
    __syncthreads();

    // ---- MFMA main: 8 m-tiles x 2 n-tiles x 4 k-steps x 3 products ----
    f32x4 zero = {0.f, 0.f, 0.f, 0.f};
    f32x4 acc[8][2];
    #pragma unroll
    for (int mt = 0; mt < 8; mt++) { acc[mt][0] = zero; acc[mt][1] = zero; }

    #pragma unroll
    for (int mt = 0; mt < 8; mt++) {
        int m = mt * 16 + l15;                  // A row (lane&15 = m)
        #pragma unroll
        for (int ks = 0; ks < 4; ks++) {
            int kc = ks * 4 + quad;             // global 16B chunk index
            int cp = kc ^ l15;                  // (m & 15) == l15
            short8 ah = *(const short8*)&sAhi[m * 128 + cp * 8];
            short8 al = *(const short8*)&sAlo[m * 128 + cp * 8];
            #pragma unroll
            for (int nt = 0; nt < 2; nt++) {
                acc[mt][nt] = __builtin_amdgcn_mfma_f32_16x16x32_bf16(ah, Bh[nt][ks], acc[mt][nt], 0, 0, 0);
                acc[mt][nt] = __builtin_amdgcn_mfma_f32_16x16x32_bf16(al, Bh[nt][ks], acc[mt][nt], 0, 0, 0);
                acc[mt][nt] = __builtin_amdgcn_mfma_f32_16x16x32_bf16(ah, Bl[nt][ks], acc[mt][nt], 0, 0, 0);
            }
        }
    }

    // ---- epilogue: store h + per-row attention dots ----
    // C/D layout: col = lane&15, row = quad*4 + r.
    float as0 = a_src[w * 32 + l15],      ad0 = a_dst[w * 32 + l15];
    float as1 = a_src[w * 32 + 16 + l15], ad1 = a_dst[w * 32 + 16 + l15];
    #pragma unroll
    for (int mt = 0; mt < 8; mt++) {
        #pragma unroll
        for (int r = 0; r < 4; r++) {
            int m = mt * 16 + quad * 4 + r;
            int g = row0 + m;
            float v0 = acc[mt][0][r], v1 = acc[mt][1][r];
            if (g < NNODES) {
                Hout[(size_t)g * 128 + w * 32 + l15]      = v0;
                Hout[(size_t)g * 128 + w * 32 + 16 + l15] = v1;
            }
            float ps = v0 * as0 + v1 * as1;
            float pd = v0 * ad0 + v1 * ad1;
            ps += __shfl_xor(ps, 1); ps += __shfl_xor(ps, 2);
            ps += __shfl_xor(ps, 4); ps += __shfl_xor(ps, 8);
            pd += __shfl_xor(pd, 1); pd += __shfl_xor(pd, 2);
            pd += __shfl_xor(pd, 4); pd += __shfl_xor(pd, 8);
            if (l15 == 0) { eS[w][m] = ps; eD[w][m] = pd; }
        }
    }
    __syncthreads();
    // combine wave-pairs per head: waves(0,1)->head0 cols 0..63, (2,3)->head1
    {
        int m = tid >> 1, head = tid & 1;
        int g = row0 + m;
        if (g < NNODES) {
            e_src[g * 2 + head] = eS[head * 2][m] + eS[head * 2 + 1][m];
            e_dst[g * 2 + head] = eD[head * 2][m] + eD[head * 2 + 1][m];
        }
    }
}

// ---------------- aggregation (8-wide unrolled gather) ----------------
// one wave per dst; lane owns channels 2L,2L+1 (head = L>=32).
// non-final layers: ReLU then write bf16 hi/lo planes (next layer's GEMM input).
__global__ __launch_bounds__(256) void k_aggregate(const float* __restrict__ h,
                                                   const float* __restrict__ e_src,
                                                   const float* __restrict__ e_dst,
                                                   const int* __restrict__ row_ptr,
                                                   const int* __restrict__ csr_src,
                                                   const float* __restrict__ bias,
                                                   float* __restrict__ outf,
                                                   unsigned short* __restrict__ ohi,
                                                   unsigned short* __restrict__ olo,
                                                   int final_layer) {
    int lane = threadIdx.x & 63;
    int wv   = threadIdx.x >> 6;
    int d    = blockIdx.x * 4 + wv;
    if (d >= NNODES) return;
    int head = lane >> 5;
    float ed = e_dst[d * 2 + head];
    int beg = row_ptr[d], end = row_ptr[d + 1];
    float accx = 0.f, accy = 0.f, ssum = 0.f;
    int j = beg;
    for (; j + 8 <= end; j += 8) {
        int s0 = csr_src[j+0], s1 = csr_src[j+1], s2 = csr_src[j+2], s3 = csr_src[j+3];
        int s4 = csr_src[j+4], s5 = csr_src[j+5], s6 = csr_src[j+6], s7 = csr_src[j+7];
        float2 h0 = *(const float2*)(h + (size_t)s0 * 128 + lane * 2);
        float2 h1 = *(const float2*)(h + (size_t)s1 * 128 + lane * 2);
        float2 h2 = *(const float2*)(h + (size_t)s2 * 128 + lane * 2);
        float2 h3 = *(const float2*)(h + (size_t)s3 * 128 + lane * 2);
        float2 h4 = *(const float2*)(h + (size_t)s4 * 128 + lane * 2);
        float2 h5 = *(const float2*)(h + (size_t)s5 * 128 + lane * 2);
        float2 h6 = *(const float2*)(h + (size_t)s6 * 128 + lane * 2);
        float2 h7 = *(const float2*)(h + (size_t)s7 * 128 + lane * 2);
        float t0 = e_src[s0*2+head] + ed, t1 = e_src[s1*2+head] + ed;
        float t2 = e_src[s2*2+head] + ed, t3 = e_src[s3*2+head] + ed;
        float t4 = e_src[s4*2+head] + ed, t5 = e_src[s5*2+head] + ed;
        float t6 = e_src[s6*2+head] + ed, t7 = e_src[s7*2+head] + ed;
        t0 = t0 > 0.f ? t0 : NEG_SLOPE * t0;  t1 = t1 > 0.f ? t1 : NEG_SLOPE * t1;
        t2 = t2 > 0.f ? t2 : NEG_SLOPE * t2;  t3 = t3 > 0.f ? t3 : NEG_SLOPE * t3;
        t4 = t4 > 0.f ? t4 : NEG_SLOPE * t4;  t5 = t5 > 0.f ? t5 : NEG_SLOPE * t5;
        t6 = t6 > 0.f ? t6 : NEG_SLOPE * t6;  t7 = t7 > 0.f ? t7 : NEG_SLOPE * t7;
        float p0 = __expf(t0), p1 = __expf(t1), p2 = __expf(t2), p3 = __expf(t3);
        float p4 = __expf(t4), p5 = __expf(t5), p6 = __expf(t6), p7 = __expf(t7);
        accx += p0*h0.x + p1*h1.x + p2*h2.x + p3*h3.x
              + p4*h4.x + p5*h5.x + p6*h6.x + p7*h7.x;
        accy += p0*h0.y + p1*h1.y + p2*h2.y + p3*h3.y
              + p4*h4.y + p5*h5.y + p6*h6.y + p7*h7.y;
        ssum += p0+p1+p2+p3+p4+p5+p6+p7;
    }
    for (; j < end; j++) {
        int s = csr_src[j];
        float t = e_src[s*2+head] + ed;
        t = t > 0.f ? t : NEG_SLOPE * t;
        float p = __expf(t);
        float2 hv = *(const float2*)(h + (size_t)s * 128 + lane * 2);
        accx += p * hv.x; accy += p * hv.y; ssum += p;
    }
    float inv = 1.0f / ssum;
    float o0 = accx * inv + bias[lane * 2];
    float o1 = accy * inv + bias[lane * 2 + 1];
    if (final_layer) {
        *(float2*)(outf + (size_t)d * 128 + lane * 2) = make_float2(o0, o1);
    } else {
        o0 = fmaxf(o0, 0.f); o1 = fmaxf(o1, 0.f);
        unsigned short h0 = f2bf(o0), h1 = f2bf(o1);
        unsigned short q0 = f2bf(o0 - bf2f(h0)), q1 = f2bf(o1 - bf2f(h1));
        *(unsigned*)&ohi[(size_t)d * 128 + lane * 2] = (unsigned)h0 | ((unsigned)h1 << 16);
        *(unsigned*)&olo[(size_t)d * 128 + lane * 2] = (unsigned)q0 | ((unsigned)q1 << 16);
    }
}

// ---------------- host ----------------

extern "C" void kernel_launch(void* const* d_in, const int* in_sizes, int n_in,
                              void* d_out, int out_size, void* d_ws, size_t ws_size,
                              hipStream_t stream) {
    const float* x  = (const float*)d_in[0];
    const int*   ei = (const int*)d_in[1];   // int32 (harness converts int64)

    char* ws = (char*)d_ws;
    size_t off = 0;
    auto alloc = [&](size_t bytes) {
        void* p = ws + off;
        off = (off + bytes + 255) & ~(size_t)255;
        return p;
    };
    int*   count   = (int*)alloc((size_t)NNODES * 4);          // reused as fill
    int*   row_ptr = (int*)alloc((size_t)(NNODES + 1) * 4);
    int*   csr     = (int*)alloc((size_t)(NEDGES + NNODES) * 4);
    float* hbuf    = (float*)alloc((size_t)NNODES * 128 * 4);
    float* es      = (float*)alloc((size_t)NNODES * 2 * 4);
    float* edv     = (float*)alloc((size_t)NNODES * 2 * 4);
    (void)ws_size; (void)in_sizes; (void)n_in; (void)out_size;

    // bf16 hi/lo activation planes live in d_out (2 x 12.8 MB = exactly 25.6 MB);
    // the final layer overwrites d_out entirely with the fp32 result.
    unsigned short* hi = (unsigned short*)d_out;
    unsigned short* lo = hi + (size_t)NNODES * 128;

    hipMemsetAsync(count, 0, (size_t)NNODES * 4, stream);
    k_count   <<<(NEDGES + 255) / 256, 256, 0, stream>>>(ei, count);
    k_scan    <<<1, 1024, 0, stream>>>(count, row_ptr);
    k_selfloop<<<(NNODES + 255) / 256, 256, 0, stream>>>(row_ptr, csr, count);
    k_scatter <<<(NEDGES + 255) / 256, 256, 0, stream>>>(ei, row_ptr, count, csr);
    k_split   <<<(NNODES * 128 / 4 + 255) / 256, 256, 0, stream>>>(x, hi, lo);

    const float* W_h = (const float*)d_in[6];
    const float* ash = (const float*)d_in[7];
    const float* adh = (const float*)d_in[8];
    const float* bh  = (const float*)d_in[9];

    struct Layer { const float *W, *as, *ad, *b; };
    Layer L[4] = {
        { (const float*)d_in[2],  (const float*)d_in[3],  (const float*)d_in[4],  (const float*)d_in[5]  },
        { W_h,              ash,        adh,        bh        },
        { W_h + 128 * 128,  ash + 128,  adh + 128,  bh + 128  },
        { (const float*)d_in[10], (const float*)d_in[11], (const float*)d_in[12], (const float*)d_in[13] },
    };

    const int gemm_blocks = (NNODES + 127) / 128;   // 391
    for (int l = 0; l < 4; l++) {
        k_gemm_mfma<<<gemm_blocks, 256, 0, stream>>>(hi, lo, L[l].W, L[l].as, L[l].ad,
                                                     hbuf, es, edv);
        k_aggregate<<<(NNODES + 3) / 4, 256, 0, stream>>>(hbuf, es, edv, row_ptr, csr,
                                                          L[l].b, (float*)d_out, hi, lo,
                                                          l == 3 ? 1 : 0);
    }
}

// Round 5
// 870.572 us; speedup vs baseline: 1.5441x; 1.0041x over previous
//
#include <hip/hip_runtime.h>

#define NNODES 50000
#define NEDGES 1600000
#define NEG_SLOPE 0.2f

typedef __attribute__((ext_vector_type(8))) short short8;
typedef __attribute__((ext_vector_type(4))) float f32x4;

static __device__ __forceinline__ unsigned short f2bf(float f) {
    unsigned u = __float_as_uint(f);
    unsigned r = u + 0x7FFFu + ((u >> 16) & 1u);   // RNE
    return (unsigned short)(r >> 16);
}
static __device__ __forceinline__ float bf2f(unsigned short h) {
    return __uint_as_float(((unsigned)h) << 16);
}

// ---------------- CSR build (edge_index arrives as int32) ----------------
// 8-wide grid-stride: 8 independent atomic chains in flight per thread.

__global__ void k_count(const int* __restrict__ ei, int* __restrict__ count) {
    int t = blockIdx.x * blockDim.x + threadIdx.x;
    int stride = gridDim.x * blockDim.x;
    #pragma unroll
    for (int i = 0; i < 8; i++) {
        int e = t + i * stride;
        if (e < NEDGES) atomicAdd(&count[ei[NEDGES + e]], 1);
    }
}

__global__ __launch_bounds__(1024) void k_scan(const int* __restrict__ count,
                                               int* __restrict__ row_ptr) {
    __shared__ int sums[1024];
    const int per = (NNODES + 1023) / 1024;
    int tid = threadIdx.x;
    int base = tid * per;
    int local = 0;
    for (int i = 0; i < per; i++) {
        int idx = base + i;
        if (idx < NNODES) local += count[idx] + 1;   // +1 = self loop
    }
    sums[tid] = local;
    __syncthreads();
    for (int off = 1; off < 1024; off <<= 1) {
        int v = 0;
        if (tid >= off) v = sums[tid - off];
        __syncthreads();
        sums[tid] += v;
        __syncthreads();
    }
    int run = sums[tid] - local;
    for (int i = 0; i < per; i++) {
        int idx = base + i;
        if (idx < NNODES) { row_ptr[idx] = run; run += count[idx] + 1; }
    }
    if (tid == 1023) row_ptr[NNODES] = sums[1023];
}

__global__ void k_selfloop(const int* __restrict__ row_ptr, int* __restrict__ csr_src,
                           int* __restrict__ fill) {
    int i = blockIdx.x * blockDim.x + threadIdx.x;
    if (i < NNODES) { csr_src[row_ptr[i]] = i; fill[i] = 1; }
}

__global__ void k_scatter(const int* __restrict__ ei, const int* __restrict__ row_ptr,
                          int* __restrict__ fill, int* __restrict__ csr_src) {
    int t = blockIdx.x * blockDim.x + threadIdx.x;
    int stride = gridDim.x * blockDim.x;
    #pragma unroll
    for (int i = 0; i < 8; i++) {
        int e = t + i * stride;
        if (e < NEDGES) {
            int s = ei[e];
            int d = ei[NEDGES + e];
            int pos = atomicAdd(&fill[d], 1);
            csr_src[row_ptr[d] + pos] = s;
        }
    }
}

// ---------------- layer-0 input split: x -> bf16 hi/lo planes ----------------

__global__ void k_split(const float* __restrict__ x, unsigned short* __restrict__ hi,
                        unsigned short* __restrict__ lo) {
    int i = blockIdx.x * blockDim.x + threadIdx.x;   // one float4 per thread
    if (i >= NNODES * 128 / 4) return;
    float4 v = *(const float4*)(x + (size_t)i * 4);
    unsigned short h0 = f2bf(v.x), h1 = f2bf(v.y), h2 = f2bf(v.z), h3 = f2bf(v.w);
    ushort4 hv = make_ushort4(h0, h1, h2, h3);
    ushort4 lv = make_ushort4(f2bf(v.x - bf2f(h0)), f2bf(v.y - bf2f(h1)),
                              f2bf(v.z - bf2f(h2)), f2bf(v.w - bf2f(h3)));
    *(ushort4*)(hi + (size_t)i * 4) = hv;
    *(ushort4*)(lo + (size_t)i * 4) = lv;
}

// ---------------- MFMA GEMM + attention-coefficient epilogue ----------------
// C = X*W via split-bf16: Xh*Wh + Xh*Wl + Xl*Wh (err ~2^-17 rel).
__global__ __launch_bounds__(256, 2) void k_gemm_mfma(
        const unsigned short* __restrict__ Ahi, const unsigned short* __restrict__ Alo,
        const float* __restrict__ W,
        const float* __restrict__ a_src, const float* __restrict__ a_dst,
        float* __restrict__ Hout, float* __restrict__ e_src, float* __restrict__ e_dst)
{
    __shared__ __align__(16) short sAhi[128 * 128];   // 32 KB
    __shared__ __align__(16) short sAlo[128 * 128];   // 32 KB
    __shared__ float eS[4][128];
    __shared__ float eD[4][128];

    const int tid  = threadIdx.x;
    const int lane = tid & 63;
    const int w    = tid >> 6;
    const int l15  = lane & 15;
    const int quad = lane >> 4;
    const int row0 = blockIdx.x * 128;

    short8 Bh[2][4], Bl[2][4];
    for (int nt = 0; nt < 2; nt++) {
        int n = w * 32 + nt * 16 + l15;
        for (int ks = 0; ks < 4; ks++) {
            short8 bh, bl;
            #pragma unroll
            for (int j = 0; j < 8; j++) {
                float wv = W[(size_t)(ks * 32 + quad * 8 + j) * 128 + n];
                unsigned short h = f2bf(wv);
                bh[j] = (short)h;
                bl[j] = (short)f2bf(wv - bf2f(h));
            }
            Bh[nt][ks] = bh; Bl[nt][ks] = bl;
        }
    }

    for (int i = tid; i < 2048; i += 256) {
        int m  = i >> 4;
        int kc = i & 15;
        int g  = row0 + m; if (g > NNODES - 1) g = NNODES - 1;
        int cp = kc ^ (m & 15);
        short8 vh = *(const short8*)(Ahi + (size_t)g * 128 + kc * 8);
        short8 vl = *(const short8*)(Alo + (size_t)g * 128 + kc * 8);
        *(short8*)&sAhi[m * 128 + cp * 8] = vh;
        *(short8*)&sAlo[m * 128 + cp * 8] = vl;
    }
    __syncthreads();

    f32x4 zero = {0.f, 0.f, 0.f, 0.f};
    f32x4 acc[8][2];
    #pragma unroll
    for (int mt = 0; mt < 8; mt++) { acc[mt][0] = zero; acc[mt][1] = zero; }

    #pragma unroll
    for (int mt = 0; mt < 8; mt++) {
        int m = mt * 16 + l15;
        #pragma unroll
        for (int ks = 0; ks < 4; ks++) {
            int kc = ks * 4 + quad;
            int cp = kc ^ l15;
            short8 ah = *(const short8*)&sAhi[m * 128 + cp * 8];
            short8 al = *(const short8*)&sAlo[m * 128 + cp * 8];
            #pragma unroll
            for (int nt = 0; nt < 2; nt++) {
                acc[mt][nt] = __builtin_amdgcn_mfma_f32_16x16x32_bf16(ah, Bh[nt][ks], acc[mt][nt], 0, 0, 0);
                acc[mt][nt] = __builtin_amdgcn_mfma_f32_16x16x32_bf16(al, Bh[nt][ks], acc[mt][nt], 0, 0, 0);
                acc[mt][nt] = __builtin_amdgcn_mfma_f32_16x16x32_bf16(ah, Bl[nt][ks], acc[mt][nt], 0, 0, 0);
            }
        }
    }

    float as0 = a_src[w * 32 + l15],      ad0 = a_dst[w * 32 + l15];
    float as1 = a_src[w * 32 + 16 + l15], ad1 = a_dst[w * 32 + 16 + l15];
    #pragma unroll
    for (int mt = 0; mt < 8; mt++) {
        #pragma unroll
        for (int r = 0; r < 4; r++) {
            int m = mt * 16 + quad * 4 + r;
            int g = row0 + m;
            float v0 = acc[mt][0][r], v1 = acc[mt][1][r];
            if (g < NNODES) {
                Hout[(size_t)g * 128 + w * 32 + l15]      = v0;
                Hout[(size_t)g * 128 + w * 32 + 16 + l15] = v1;
            }
            float ps = v0 * as0 + v1 * as1;
            float pd = v0 * ad0 + v1 * ad1;
            ps += __shfl_xor(ps, 1); ps += __shfl_xor(ps, 2);
            ps += __shfl_xor(ps, 4); ps += __shfl_xor(ps, 8);
            pd += __shfl_xor(pd, 1); pd += __shfl_xor(pd, 2);
            pd += __shfl_xor(pd, 4); pd += __shfl_xor(pd, 8);
            if (l15 == 0) { eS[w][m] = ps; eD[w][m] = pd; }
        }
    }
    __syncthreads();
    {
        int m = tid >> 1, head = tid & 1;
        int g = row0 + m;
        if (g < NNODES) {
            e_src[g * 2 + head] = eS[head * 2][m] + eS[head * 2 + 1][m];
            e_dst[g * 2 + head] = eD[head * 2][m] + eD[head * 2 + 1][m];
        }
    }
}

// ---------------- aggregation ----------------
// one wave per dst; float4/lane: half = lane>>5 picks edge parity, li = lane&31
// owns channels 4li..4li+3 (head = li>>4). One 16B gather instruction covers
// TWO edge rows (lanes 0-31 = edge j, lanes 32-63 = edge j+1): halves address
// math / csr / e_src / exp work vs float2 layout. shfl_xor(32) merges halves.
__global__ __launch_bounds__(256) void k_aggregate(const float* __restrict__ h,
                                                   const float* __restrict__ e_src,
                                                   const float* __restrict__ e_dst,
                                                   const int* __restrict__ row_ptr,
                                                   const int* __restrict__ csr_src,
                                                   const float* __restrict__ bias,
                                                   float* __restrict__ outf,
                                                   unsigned short* __restrict__ ohi,
                                                   unsigned short* __restrict__ olo,
                                                   int final_layer) {
    int lane = threadIdx.x & 63;
    int wv   = threadIdx.x >> 6;
    int d    = blockIdx.x * 4 + wv;
    if (d >= NNODES) return;
    int half = lane >> 5;
    int li   = lane & 31;
    int head = li >> 4;
    int c0   = li * 4;
    float ed = e_dst[d * 2 + head];
    int beg = row_ptr[d], end = row_ptr[d + 1];
    f32x4 acc = {0.f, 0.f, 0.f, 0.f};
    float ssum = 0.f;
    int j = beg;
    for (; j + 8 <= end; j += 8) {
        int i0 = j + half, i1 = j + 2 + half, i2 = j + 4 + half, i3 = j + 6 + half;
        int s0 = csr_src[i0], s1 = csr_src[i1], s2 = csr_src[i2], s3 = csr_src[i3];
        f32x4 h0 = *(const f32x4*)(h + (size_t)s0 * 128 + c0);
        f32x4 h1 = *(const f32x4*)(h + (size_t)s1 * 128 + c0);
        f32x4 h2 = *(const f32x4*)(h + (size_t)s2 * 128 + c0);
        f32x4 h3 = *(const f32x4*)(h + (size_t)s3 * 128 + c0);
        float t0 = e_src[s0*2+head] + ed, t1 = e_src[s1*2+head] + ed;
        float t2 = e_src[s2*2+head] + ed, t3 = e_src[s3*2+head] + ed;
        t0 = t0 > 0.f ? t0 : NEG_SLOPE * t0;  t1 = t1 > 0.f ? t1 : NEG_SLOPE * t1;
        t2 = t2 > 0.f ? t2 : NEG_SLOPE * t2;  t3 = t3 > 0.f ? t3 : NEG_SLOPE * t3;
        float p0 = __expf(t0), p1 = __expf(t1), p2 = __expf(t2), p3 = __expf(t3);
        acc += p0 * h0 + p1 * h1 + p2 * h2 + p3 * h3;
        ssum += p0 + p1 + p2 + p3;
    }
    for (; j < end; j += 2) {
        int idx = j + half;
        bool valid = idx < end;
        int s = csr_src[valid ? idx : end - 1];
        float t = e_src[s*2+head] + ed;
        t = t > 0.f ? t : NEG_SLOPE * t;
        float p = valid ? __expf(t) : 0.f;
        f32x4 hv = *(const f32x4*)(h + (size_t)s * 128 + c0);
        acc += p * hv;
        ssum += p;
    }
    // merge the two edge-parity halves
    acc[0] += __shfl_xor(acc[0], 32);
    acc[1] += __shfl_xor(acc[1], 32);
    acc[2] += __shfl_xor(acc[2], 32);
    acc[3] += __shfl_xor(acc[3], 32);
    ssum   += __shfl_xor(ssum,   32);
    if (half == 0) {
        float inv = 1.0f / ssum;
        float4 bv = *(const float4*)(bias + c0);
        float o0 = acc[0] * inv + bv.x;
        float o1 = acc[1] * inv + bv.y;
        float o2 = acc[2] * inv + bv.z;
        float o3 = acc[3] * inv + bv.w;
        if (final_layer) {
            *(float4*)(outf + (size_t)d * 128 + c0) = make_float4(o0, o1, o2, o3);
        } else {
            o0 = fmaxf(o0, 0.f); o1 = fmaxf(o1, 0.f);
            o2 = fmaxf(o2, 0.f); o3 = fmaxf(o3, 0.f);
            unsigned short h0 = f2bf(o0), h1 = f2bf(o1), h2 = f2bf(o2), h3 = f2bf(o3);
            *(ushort4*)&ohi[(size_t)d * 128 + c0] = make_ushort4(h0, h1, h2, h3);
            *(ushort4*)&olo[(size_t)d * 128 + c0] =
                make_ushort4(f2bf(o0 - bf2f(h0)), f2bf(o1 - bf2f(h1)),
                             f2bf(o2 - bf2f(h2)), f2bf(o3 - bf2f(h3)));
        }
    }
}

// ---------------- host ----------------

extern "C" void kernel_launch(void* const* d_in, const int* in_sizes, int n_in,
                              void* d_out, int out_size, void* d_ws, size_t ws_size,
                              hipStream_t stream) {
    const float* x  = (const float*)d_in[0];
    const int*   ei = (const int*)d_in[1];   // int32 (harness converts int64)

    char* ws = (char*)d_ws;
    size_t off = 0;
    auto alloc = [&](size_t bytes) {
        void* p = ws + off;
        off = (off + bytes + 255) & ~(size_t)255;
        return p;
    };
    int*   count   = (int*)alloc((size_t)NNODES * 4);
    int*   row_ptr = (int*)alloc((size_t)(NNODES + 1) * 4);
    int*   csr     = (int*)alloc((size_t)(NEDGES + NNODES) * 4);
    float* hbuf    = (float*)alloc((size_t)NNODES * 128 * 4);
    float* es      = (float*)alloc((size_t)NNODES * 2 * 4);
    float* edv     = (float*)alloc((size_t)NNODES * 2 * 4);
    (void)ws_size; (void)in_sizes; (void)n_in; (void)out_size;

    unsigned short* hi = (unsigned short*)d_out;
    unsigned short* lo = hi + (size_t)NNODES * 128;

    const int ecsr_blocks = (NEDGES + 8 * 256 - 1) / (8 * 256);   // 782

    hipMemsetAsync(count, 0, (size_t)NNODES * 4, stream);
    k_count   <<<ecsr_blocks, 256, 0, stream>>>(ei, count);
    k_scan    <<<1, 1024, 0, stream>>>(count, row_ptr);
    k_selfloop<<<(NNODES + 255) / 256, 256, 0, stream>>>(row_ptr, csr, count);
    k_scatter <<<ecsr_blocks, 256, 0, stream>>>(ei, row_ptr, count, csr);
    k_split   <<<(NNODES * 128 / 4 + 255) / 256, 256, 0, stream>>>(x, hi, lo);

    const float* W_h = (const float*)d_in[6];
    const float* ash = (const float*)d_in[7];
    const float* adh = (const float*)d_in[8];
    const float* bh  = (const float*)d_in[9];

    struct Layer { const float *W, *as, *ad, *b; };
    Layer L[4] = {
        { (const float*)d_in[2],  (const float*)d_in[3],  (const float*)d_in[4],  (const float*)d_in[5]  },
        { W_h,              ash,        adh,        bh        },
        { W_h + 128 * 128,  ash + 128,  adh + 128,  bh + 128  },
        { (const float*)d_in[10], (const float*)d_in[11], (const float*)d_in[12], (const float*)d_in[13] },
    };

    const int gemm_blocks = (NNODES + 127) / 128;   // 391
    for (int l = 0; l < 4; l++) {
        k_gemm_mfma<<<gemm_blocks, 256, 0, stream>>>(hi, lo, L[l].W, L[l].as, L[l].ad,
                                                     hbuf, es, edv);
        k_aggregate<<<(NNODES + 3) / 4, 256, 0, stream>>>(hbuf, es, edv, row_ptr, csr,
                                                          L[l].b, (float*)d_out, hi, lo,
                                                          l == 3 ? 1 : 0);
    }
}

// Round 6
// 834.620 us; speedup vs baseline: 1.6106x; 1.0431x over previous
//
#include <hip/hip_runtime.h>

#define NNODES 50000
#define NEDGES 1600000
#define NEG_SLOPE 0.2f

typedef __attribute__((ext_vector_type(8))) short short8;
typedef __attribute__((ext_vector_type(4))) float f32x4;

static __device__ __forceinline__ unsigned short f2bf(float f) {
    unsigned u = __float_as_uint(f);
    unsigned r = u + 0x7FFFu + ((u >> 16) & 1u);   // RNE
    return (unsigned short)(r >> 16);
}
static __device__ __forceinline__ float bf2f(unsigned short h) {
    return __uint_as_float(((unsigned)h) << 16);
}

// ---------------- CSR build (edge_index arrives as int32) ----------------
// count pass also persists each edge's within-bucket rank (the atomicAdd
// return we previously discarded) -> scatter pass needs NO atomics.

__global__ void k_count(const int* __restrict__ ei, int* __restrict__ count,
                        int* __restrict__ pos) {
    int t = blockIdx.x * blockDim.x + threadIdx.x;
    int stride = gridDim.x * blockDim.x;
    #pragma unroll
    for (int i = 0; i < 8; i++) {
        int e = t + i * stride;
        if (e < NEDGES) pos[e] = atomicAdd(&count[ei[NEDGES + e]], 1);
    }
}

__global__ __launch_bounds__(1024) void k_scan(const int* __restrict__ count,
                                               int* __restrict__ row_ptr) {
    __shared__ int sums[1024];
    const int per = (NNODES + 1023) / 1024;
    int tid = threadIdx.x;
    int base = tid * per;
    int local = 0;
    for (int i = 0; i < per; i++) {
        int idx = base + i;
        if (idx < NNODES) local += count[idx] + 1;   // +1 = self loop
    }
    sums[tid] = local;
    __syncthreads();
    for (int off = 1; off < 1024; off <<= 1) {
        int v = 0;
        if (tid >= off) v = sums[tid - off];
        __syncthreads();
        sums[tid] += v;
        __syncthreads();
    }
    int run = sums[tid] - local;
    for (int i = 0; i < per; i++) {
        int idx = base + i;
        if (idx < NNODES) { row_ptr[idx] = run; run += count[idx] + 1; }
    }
    if (tid == 1023) row_ptr[NNODES] = sums[1023];
}

__global__ void k_selfloop(const int* __restrict__ row_ptr, int* __restrict__ csr_src) {
    int i = blockIdx.x * blockDim.x + threadIdx.x;
    if (i < NNODES) csr_src[row_ptr[i]] = i;
}

// atomic-free scatter: slot = row_ptr[d] + 1 + pos[e]; nontemporal store
// (partial random lines merge at the memory-side Infinity Cache).
__global__ void k_scatter(const int* __restrict__ ei, const int* __restrict__ row_ptr,
                          const int* __restrict__ pos, int* __restrict__ csr_src) {
    int t = blockIdx.x * blockDim.x + threadIdx.x;
    int stride = gridDim.x * blockDim.x;
    #pragma unroll
    for (int i = 0; i < 4; i++) {
        int e = t + i * stride;
        if (e < NEDGES) {
            int s = ei[e];
            int d = ei[NEDGES + e];
            __builtin_nontemporal_store(s, &csr_src[row_ptr[d] + 1 + pos[e]]);
        }
    }
}

// ---------------- layer-0 input split: x -> bf16 hi/lo planes ----------------

__global__ void k_split(const float* __restrict__ x, unsigned short* __restrict__ hi,
                        unsigned short* __restrict__ lo) {
    int i = blockIdx.x * blockDim.x + threadIdx.x;   // one float4 per thread
    if (i >= NNODES * 128 / 4) return;
    float4 v = *(const float4*)(x + (size_t)i * 4);
    unsigned short h0 = f2bf(v.x), h1 = f2bf(v.y), h2 = f2bf(v.z), h3 = f2bf(v.w);
    ushort4 hv = make_ushort4(h0, h1, h2, h3);
    ushort4 lv = make_ushort4(f2bf(v.x - bf2f(h0)), f2bf(v.y - bf2f(h1)),
                              f2bf(v.z - bf2f(h2)), f2bf(v.w - bf2f(h3)));
    *(ushort4*)(hi + (size_t)i * 4) = hv;
    *(ushort4*)(lo + (size_t)i * 4) = lv;
}

// ---------------- MFMA GEMM + attention-coefficient epilogue ----------------
// C = X*W via split-bf16: Xh*Wh + Xh*Wl + Xl*Wh (err ~2^-17 rel).
__global__ __launch_bounds__(256, 2) void k_gemm_mfma(
        const unsigned short* __restrict__ Ahi, const unsigned short* __restrict__ Alo,
        const float* __restrict__ W,
        const float* __restrict__ a_src, const float* __restrict__ a_dst,
        float* __restrict__ Hout, float* __restrict__ e_src, float* __restrict__ e_dst)
{
    __shared__ __align__(16) short sAhi[128 * 128];   // 32 KB
    __shared__ __align__(16) short sAlo[128 * 128];   // 32 KB
    __shared__ float eS[4][128];
    __shared__ float eD[4][128];

    const int tid  = threadIdx.x;
    const int lane = tid & 63;
    const int w    = tid >> 6;
    const int l15  = lane & 15;
    const int quad = lane >> 4;
    const int row0 = blockIdx.x * 128;

    short8 Bh[2][4], Bl[2][4];
    for (int nt = 0; nt < 2; nt++) {
        int n = w * 32 + nt * 16 + l15;
        for (int ks = 0; ks < 4; ks++) {
            short8 bh, bl;
            #pragma unroll
            for (int j = 0; j < 8; j++) {
                float wv = W[(size_t)(ks * 32 + quad * 8 + j) * 128 + n];
                unsigned short h = f2bf(wv);
                bh[j] = (short)h;
                bl[j] = (short)f2bf(wv - bf2f(h));
            }
            Bh[nt][ks] = bh; Bl[nt][ks] = bl;
        }
    }

    for (int i = tid; i < 2048; i += 256) {
        int m  = i >> 4;
        int kc = i & 15;
        int g  = row0 + m; if (g > NNODES - 1) g = NNODES - 1;
        int cp = kc ^ (m & 15);
        short8 vh = *(const short8*)(Ahi + (size_t)g * 128 + kc * 8);
        short8 vl = *(const short8*)(Alo + (size_t)g * 128 + kc * 8);
        *(short8*)&sAhi[m * 128 + cp * 8] = vh;
        *(short8*)&sAlo[m * 128 + cp * 8] = vl;
    }
    __syncthreads();

    f32x4 zero = {0.f, 0.f, 0.f, 0.f};
    f32x4 acc[8][2];
    #pragma unroll
    for (int mt = 0; mt < 8; mt++) { acc[mt][0] = zero; acc[mt][1] = zero; }

    #pragma unroll
    for (int mt = 0; mt < 8; mt++) {
        int m = mt * 16 + l15;
        #pragma unroll
        for (int ks = 0; ks < 4; ks++) {
            int kc = ks * 4 + quad;
            int cp = kc ^ l15;
            short8 ah = *(const short8*)&sAhi[m * 128 + cp * 8];
            short8 al = *(const short8*)&sAlo[m * 128 + cp * 8];
            #pragma unroll
            for (int nt = 0; nt < 2; nt++) {
                acc[mt][nt] = __builtin_amdgcn_mfma_f32_16x16x32_bf16(ah, Bh[nt][ks], acc[mt][nt], 0, 0, 0);
                acc[mt][nt] = __builtin_amdgcn_mfma_f32_16x16x32_bf16(al, Bh[nt][ks], acc[mt][nt], 0, 0, 0);
                acc[mt][nt] = __builtin_amdgcn_mfma_f32_16x16x32_bf16(ah, Bl[nt][ks], acc[mt][nt], 0, 0, 0);
            }
        }
    }

    float as0 = a_src[w * 32 + l15],      ad0 = a_dst[w * 32 + l15];
    float as1 = a_src[w * 32 + 16 + l15], ad1 = a_dst[w * 32 + 16 + l15];
    #pragma unroll
    for (int mt = 0; mt < 8; mt++) {
        #pragma unroll
        for (int r = 0; r < 4; r++) {
            int m = mt * 16 + quad * 4 + r;
            int g = row0 + m;
            float v0 = acc[mt][0][r], v1 = acc[mt][1][r];
            if (g < NNODES) {
                Hout[(size_t)g * 128 + w * 32 + l15]      = v0;
                Hout[(size_t)g * 128 + w * 32 + 16 + l15] = v1;
            }
            float ps = v0 * as0 + v1 * as1;
            float pd = v0 * ad0 + v1 * ad1;
            ps += __shfl_xor(ps, 1); ps += __shfl_xor(ps, 2);
            ps += __shfl_xor(ps, 4); ps += __shfl_xor(ps, 8);
            pd += __shfl_xor(pd, 1); pd += __shfl_xor(pd, 2);
            pd += __shfl_xor(pd, 4); pd += __shfl_xor(pd, 8);
            if (l15 == 0) { eS[w][m] = ps; eD[w][m] = pd; }
        }
    }
    __syncthreads();
    {
        int m = tid >> 1, head = tid & 1;
        int g = row0 + m;
        if (g < NNODES) {
            e_src[g * 2 + head] = eS[head * 2][m] + eS[head * 2 + 1][m];
            e_dst[g * 2 + head] = eD[head * 2][m] + eD[head * 2 + 1][m];
        }
    }
}

// ---------------- aggregation ----------------
// one wave per dst; float4/lane, lanes 0-31 = edge j, 32-63 = edge j+1.
// 16-edge pipeline: 8 independent 16B-gather instructions in flight per wave.
__global__ __launch_bounds__(256) void k_aggregate(const float* __restrict__ h,
                                                   const float* __restrict__ e_src,
                                                   const float* __restrict__ e_dst,
                                                   const int* __restrict__ row_ptr,
                                                   const int* __restrict__ csr_src,
                                                   const float* __restrict__ bias,
                                                   float* __restrict__ outf,
                                                   unsigned short* __restrict__ ohi,
                                                   unsigned short* __restrict__ olo,
                                                   int final_layer) {
    int lane = threadIdx.x & 63;
    int wv   = threadIdx.x >> 6;
    int d    = blockIdx.x * 4 + wv;
    if (d >= NNODES) return;
    int half = lane >> 5;
    int li   = lane & 31;
    int head = li >> 4;
    int c0   = li * 4;
    float ed = e_dst[d * 2 + head];
    int beg = row_ptr[d], end = row_ptr[d + 1];
    f32x4 acc = {0.f, 0.f, 0.f, 0.f};
    float ssum = 0.f;
    int j = beg;
    for (; j + 16 <= end; j += 16) {
        int s0 = csr_src[j +  0 + half], s1 = csr_src[j +  2 + half];
        int s2 = csr_src[j +  4 + half], s3 = csr_src[j +  6 + half];
        int s4 = csr_src[j +  8 + half], s5 = csr_src[j + 10 + half];
        int s6 = csr_src[j + 12 + half], s7 = csr_src[j + 14 + half];
        f32x4 h0 = *(const f32x4*)(h + (size_t)s0 * 128 + c0);
        f32x4 h1 = *(const f32x4*)(h + (size_t)s1 * 128 + c0);
        f32x4 h2 = *(const f32x4*)(h + (size_t)s2 * 128 + c0);
        f32x4 h3 = *(const f32x4*)(h + (size_t)s3 * 128 + c0);
        f32x4 h4 = *(const f32x4*)(h + (size_t)s4 * 128 + c0);
        f32x4 h5 = *(const f32x4*)(h + (size_t)s5 * 128 + c0);
        f32x4 h6 = *(const f32x4*)(h + (size_t)s6 * 128 + c0);
        f32x4 h7 = *(const f32x4*)(h + (size_t)s7 * 128 + c0);
        float t0 = e_src[s0*2+head] + ed, t1 = e_src[s1*2+head] + ed;
        float t2 = e_src[s2*2+head] + ed, t3 = e_src[s3*2+head] + ed;
        float t4 = e_src[s4*2+head] + ed, t5 = e_src[s5*2+head] + ed;
        float t6 = e_src[s6*2+head] + ed, t7 = e_src[s7*2+head] + ed;
        t0 = t0 > 0.f ? t0 : NEG_SLOPE * t0;  t1 = t1 > 0.f ? t1 : NEG_SLOPE * t1;
        t2 = t2 > 0.f ? t2 : NEG_SLOPE * t2;  t3 = t3 > 0.f ? t3 : NEG_SLOPE * t3;
        t4 = t4 > 0.f ? t4 : NEG_SLOPE * t4;  t5 = t5 > 0.f ? t5 : NEG_SLOPE * t5;
        t6 = t6 > 0.f ? t6 : NEG_SLOPE * t6;  t7 = t7 > 0.f ? t7 : NEG_SLOPE * t7;
        float p0 = __expf(t0), p1 = __expf(t1), p2 = __expf(t2), p3 = __expf(t3);
        float p4 = __expf(t4), p5 = __expf(t5), p6 = __expf(t6), p7 = __expf(t7);
        acc += p0 * h0 + p1 * h1 + p2 * h2 + p3 * h3
             + p4 * h4 + p5 * h5 + p6 * h6 + p7 * h7;
        ssum += p0 + p1 + p2 + p3 + p4 + p5 + p6 + p7;
    }
    for (; j + 8 <= end; j += 8) {
        int s0 = csr_src[j + half],     s1 = csr_src[j + 2 + half];
        int s2 = csr_src[j + 4 + half], s3 = csr_src[j + 6 + half];
        f32x4 h0 = *(const f32x4*)(h + (size_t)s0 * 128 + c0);
        f32x4 h1 = *(const f32x4*)(h + (size_t)s1 * 128 + c0);
        f32x4 h2 = *(const f32x4*)(h + (size_t)s2 * 128 + c0);
        f32x4 h3 = *(const f32x4*)(h + (size_t)s3 * 128 + c0);
        float t0 = e_src[s0*2+head] + ed, t1 = e_src[s1*2+head] + ed;
        float t2 = e_src[s2*2+head] + ed, t3 = e_src[s3*2+head] + ed;
        t0 = t0 > 0.f ? t0 : NEG_SLOPE * t0;  t1 = t1 > 0.f ? t1 : NEG_SLOPE * t1;
        t2 = t2 > 0.f ? t2 : NEG_SLOPE * t2;  t3 = t3 > 0.f ? t3 : NEG_SLOPE * t3;
        float p0 = __expf(t0), p1 = __expf(t1), p2 = __expf(t2), p3 = __expf(t3);
        acc += p0 * h0 + p1 * h1 + p2 * h2 + p3 * h3;
        ssum += p0 + p1 + p2 + p3;
    }
    for (; j < end; j += 2) {
        int idx = j + half;
        bool valid = idx < end;
        int s = csr_src[valid ? idx : end - 1];
        float t = e_src[s*2+head] + ed;
        t = t > 0.f ? t : NEG_SLOPE * t;
        float p = valid ? __expf(t) : 0.f;
        f32x4 hv = *(const f32x4*)(h + (size_t)s * 128 + c0);
        acc += p * hv;
        ssum += p;
    }
    acc[0] += __shfl_xor(acc[0], 32);
    acc[1] += __shfl_xor(acc[1], 32);
    acc[2] += __shfl_xor(acc[2], 32);
    acc[3] += __shfl_xor(acc[3], 32);
    ssum   += __shfl_xor(ssum,   32);
    if (half == 0) {
        float inv = 1.0f / ssum;
        float4 bv = *(const float4*)(bias + c0);
        float o0 = acc[0] * inv + bv.x;
        float o1 = acc[1] * inv + bv.y;
        float o2 = acc[2] * inv + bv.z;
        float o3 = acc[3] * inv + bv.w;
        if (final_layer) {
            *(float4*)(outf + (size_t)d * 128 + c0) = make_float4(o0, o1, o2, o3);
        } else {
            o0 = fmaxf(o0, 0.f); o1 = fmaxf(o1, 0.f);
            o2 = fmaxf(o2, 0.f); o3 = fmaxf(o3, 0.f);
            unsigned short h0 = f2bf(o0), h1 = f2bf(o1), h2 = f2bf(o2), h3 = f2bf(o3);
            *(ushort4*)&ohi[(size_t)d * 128 + c0] = make_ushort4(h0, h1, h2, h3);
            *(ushort4*)&olo[(size_t)d * 128 + c0] =
                make_ushort4(f2bf(o0 - bf2f(h0)), f2bf(o1 - bf2f(h1)),
                             f2bf(o2 - bf2f(h2)), f2bf(o3 - bf2f(h3)));
        }
    }
}

// ---------------- host ----------------

extern "C" void kernel_launch(void* const* d_in, const int* in_sizes, int n_in,
                              void* d_out, int out_size, void* d_ws, size_t ws_size,
                              hipStream_t stream) {
    const float* x  = (const float*)d_in[0];
    const int*   ei = (const int*)d_in[1];   // int32 (harness converts int64)

    char* ws = (char*)d_ws;
    size_t off = 0;
    auto alloc = [&](size_t bytes) {
        void* p = ws + off;
        off = (off + bytes + 255) & ~(size_t)255;
        return p;
    };
    int*   count   = (int*)alloc((size_t)NNODES * 4);
    int*   row_ptr = (int*)alloc((size_t)(NNODES + 1) * 4);
    int*   csr     = (int*)alloc((size_t)(NEDGES + NNODES) * 4);
    int*   pos     = (int*)alloc((size_t)NEDGES * 4);
    float* hbuf    = (float*)alloc((size_t)NNODES * 128 * 4);
    float* es      = (float*)alloc((size_t)NNODES * 2 * 4);
    float* edv     = (float*)alloc((size_t)NNODES * 2 * 4);
    (void)ws_size; (void)in_sizes; (void)n_in; (void)out_size;

    unsigned short* hi = (unsigned short*)d_out;
    unsigned short* lo = hi + (size_t)NNODES * 128;

    hipMemsetAsync(count, 0, (size_t)NNODES * 4, stream);
    k_count   <<<(NEDGES + 8 * 256 - 1) / (8 * 256), 256, 0, stream>>>(ei, count, pos);
    k_scan    <<<1, 1024, 0, stream>>>(count, row_ptr);
    k_selfloop<<<(NNODES + 255) / 256, 256, 0, stream>>>(row_ptr, csr);
    k_scatter <<<(NEDGES + 4 * 256 - 1) / (4 * 256), 256, 0, stream>>>(ei, row_ptr, pos, csr);
    k_split   <<<(NNODES * 128 / 4 + 255) / 256, 256, 0, stream>>>(x, hi, lo);

    const float* W_h = (const float*)d_in[6];
    const float* ash = (const float*)d_in[7];
    const float* adh = (const float*)d_in[8];
    const float* bh  = (const float*)d_in[9];

    struct Layer { const float *W, *as, *ad, *b; };
    Layer L[4] = {
        { (const float*)d_in[2],  (const float*)d_in[3],  (const float*)d_in[4],  (const float*)d_in[5]  },
        { W_h,              ash,        adh,        bh        },
        { W_h + 128 * 128,  ash + 128,  adh + 128,  bh + 128  },
        { (const float*)d_in[10], (const float*)d_in[11], (const float*)d_in[12], (const float*)d_in[13] },
    };

    const int gemm_blocks = (NNODES + 127) / 128;   // 391
    for (int l = 0; l < 4; l++) {
        k_gemm_mfma<<<gemm_blocks, 256, 0, stream>>>(hi, lo, L[l].W, L[l].as, L[l].ad,
                                                     hbuf, es, edv);
        k_aggregate<<<(NNODES + 3) / 4, 256, 0, stream>>>(hbuf, es, edv, row_ptr, csr,
                                                          L[l].b, (float*)d_out, hi, lo,
                                                          l == 3 ? 1 : 0);
    }
}

// Round 7
// 729.543 us; speedup vs baseline: 1.8426x; 1.1440x over previous
//
#include <hip/hip_runtime.h>

#define NNODES 50000
#define NEDGES 1600000
#define NEG_SLOPE 0.2f

typedef __attribute__((ext_vector_type(8))) short short8;
typedef __attribute__((ext_vector_type(4))) float f32x4;
typedef __attribute__((ext_vector_type(4))) unsigned short us4;
typedef __attribute__((ext_vector_type(4))) unsigned int u32x4;

static __device__ __forceinline__ unsigned short f2bf(float f) {
    unsigned u = __float_as_uint(f);
    unsigned r = u + 0x7FFFu + ((u >> 16) & 1u);   // RNE
    return (unsigned short)(r >> 16);
}
static __device__ __forceinline__ float bf2f(unsigned short h) {
    return __uint_as_float(((unsigned)h) << 16);
}
static __device__ __forceinline__ unsigned short f2h(float f) {
    union { _Float16 x; unsigned short u; } c;
    c.x = (_Float16)f;
    return c.u;
}
static __device__ __forceinline__ float h2f(unsigned short u) {
    union { unsigned short u; _Float16 x; } c;
    c.u = u;
    return (float)c.x;
}

// ---------------- CSR build (edge_index arrives as int32) ----------------

__global__ void k_count(const int* __restrict__ ei, int* __restrict__ count,
                        int* __restrict__ pos) {
    int t = blockIdx.x * blockDim.x + threadIdx.x;
    int stride = gridDim.x * blockDim.x;
    #pragma unroll
    for (int i = 0; i < 8; i++) {
        int e = t + i * stride;
        if (e < NEDGES) pos[e] = atomicAdd(&count[ei[NEDGES + e]], 1);
    }
}

__global__ __launch_bounds__(1024) void k_scan(const int* __restrict__ count,
                                               int* __restrict__ row_ptr) {
    __shared__ int sums[1024];
    const int per = (NNODES + 1023) / 1024;
    int tid = threadIdx.x;
    int base = tid * per;
    int local = 0;
    for (int i = 0; i < per; i++) {
        int idx = base + i;
        if (idx < NNODES) local += count[idx] + 1;   // +1 = self loop
    }
    sums[tid] = local;
    __syncthreads();
    for (int off = 1; off < 1024; off <<= 1) {
        int v = 0;
        if (tid >= off) v = sums[tid - off];
        __syncthreads();
        sums[tid] += v;
        __syncthreads();
    }
    int run = sums[tid] - local;
    for (int i = 0; i < per; i++) {
        int idx = base + i;
        if (idx < NNODES) { row_ptr[idx] = run; run += count[idx] + 1; }
    }
    if (tid == 1023) row_ptr[NNODES] = sums[1023];
}

__global__ void k_selfloop(const int* __restrict__ row_ptr, int* __restrict__ csr_src) {
    int i = blockIdx.x * blockDim.x + threadIdx.x;
    if (i < NNODES) csr_src[row_ptr[i]] = i;
}

__global__ void k_scatter(const int* __restrict__ ei, const int* __restrict__ row_ptr,
                          const int* __restrict__ pos, int* __restrict__ csr_src) {
    int t = blockIdx.x * blockDim.x + threadIdx.x;
    int stride = gridDim.x * blockDim.x;
    #pragma unroll
    for (int i = 0; i < 4; i++) {
        int e = t + i * stride;
        if (e < NEDGES) {
            int s = ei[e];
            int d = ei[NEDGES + e];
            __builtin_nontemporal_store(s, &csr_src[row_ptr[d] + 1 + pos[e]]);
        }
    }
}

// ---------------- layer-0 input split: x -> bf16 hi/lo planes ----------------

__global__ void k_split(const float* __restrict__ x, unsigned short* __restrict__ hi,
                        unsigned short* __restrict__ lo) {
    int i = blockIdx.x * blockDim.x + threadIdx.x;
    if (i >= NNODES * 128 / 4) return;
    float4 v = *(const float4*)(x + (size_t)i * 4);
    unsigned short h0 = f2bf(v.x), h1 = f2bf(v.y), h2 = f2bf(v.z), h3 = f2bf(v.w);
    *(ushort4*)(hi + (size_t)i * 4) = make_ushort4(h0, h1, h2, h3);
    *(ushort4*)(lo + (size_t)i * 4) =
        make_ushort4(f2bf(v.x - bf2f(h0)), f2bf(v.y - bf2f(h1)),
                     f2bf(v.z - bf2f(h2)), f2bf(v.w - bf2f(h3)));
}

// ---------------- MFMA GEMM + attention-coefficient epilogue ----------------
// C = X*W via split-bf16: Xh*Wh + Xh*Wl + Xl*Wh (err ~2^-17 rel).
// Epilogue writes h for the aggregation gather:
//   hidden layers: fp16 plane (256 B rows -> halves the gather wall traffic)
//   final layer:   packed (fp16 hi | fp16 lo) uint plane (~2^-21, exact-ish)
__global__ __launch_bounds__(256, 2) void k_gemm_mfma(
        const unsigned short* __restrict__ Ahi, const unsigned short* __restrict__ Alo,
        const float* __restrict__ W,
        const float* __restrict__ a_src, const float* __restrict__ a_dst,
        unsigned short* __restrict__ Hhi, unsigned* __restrict__ Hpk,
        float* __restrict__ e_src, float* __restrict__ e_dst, int final_layer)
{
    __shared__ __align__(16) short sAhi[128 * 128];   // 32 KB
    __shared__ __align__(16) short sAlo[128 * 128];   // 32 KB
    __shared__ float eS[4][128];
    __shared__ float eD[4][128];

    const int tid  = threadIdx.x;
    const int lane = tid & 63;
    const int w    = tid >> 6;
    const int l15  = lane & 15;
    const int quad = lane >> 4;
    const int row0 = blockIdx.x * 128;

    short8 Bh[2][4], Bl[2][4];
    for (int nt = 0; nt < 2; nt++) {
        int n = w * 32 + nt * 16 + l15;
        for (int ks = 0; ks < 4; ks++) {
            short8 bh, bl;
            #pragma unroll
            for (int j = 0; j < 8; j++) {
                float wv = W[(size_t)(ks * 32 + quad * 8 + j) * 128 + n];
                unsigned short h = f2bf(wv);
                bh[j] = (short)h;
                bl[j] = (short)f2bf(wv - bf2f(h));
            }
            Bh[nt][ks] = bh; Bl[nt][ks] = bl;
        }
    }

    for (int i = tid; i < 2048; i += 256) {
        int m  = i >> 4;
        int kc = i & 15;
        int g  = row0 + m; if (g > NNODES - 1) g = NNODES - 1;
        int cp = kc ^ (m & 15);
        short8 vh = *(const short8*)(Ahi + (size_t)g * 128 + kc * 8);
        short8 vl = *(const short8*)(Alo + (size_t)g * 128 + kc * 8);
        *(short8*)&sAhi[m * 128 + cp * 8] = vh;
        *(short8*)&sAlo[m * 128 + cp * 8] = vl;
    }
    __syncthreads();

    f32x4 zero = {0.f, 0.f, 0.f, 0.f};
    f32x4 acc[8][2];
    #pragma unroll
    for (int mt = 0; mt < 8; mt++) { acc[mt][0] = zero; acc[mt][1] = zero; }

    #pragma unroll
    for (int mt = 0; mt < 8; mt++) {
        int m = mt * 16 + l15;
        #pragma unroll
        for (int ks = 0; ks < 4; ks++) {
            int kc = ks * 4 + quad;
            int cp = kc ^ l15;
            short8 ah = *(const short8*)&sAhi[m * 128 + cp * 8];
            short8 al = *(const short8*)&sAlo[m * 128 + cp * 8];
            #pragma unroll
            for (int nt = 0; nt < 2; nt++) {
                acc[mt][nt] = __builtin_amdgcn_mfma_f32_16x16x32_bf16(ah, Bh[nt][ks], acc[mt][nt], 0, 0, 0);
                acc[mt][nt] = __builtin_amdgcn_mfma_f32_16x16x32_bf16(al, Bh[nt][ks], acc[mt][nt], 0, 0, 0);
                acc[mt][nt] = __builtin_amdgcn_mfma_f32_16x16x32_bf16(ah, Bl[nt][ks], acc[mt][nt], 0, 0, 0);
            }
        }
    }

    float as0 = a_src[w * 32 + l15],      ad0 = a_dst[w * 32 + l15];
    float as1 = a_src[w * 32 + 16 + l15], ad1 = a_dst[w * 32 + 16 + l15];
    #pragma unroll
    for (int mt = 0; mt < 8; mt++) {
        #pragma unroll
        for (int r = 0; r < 4; r++) {
            int m = mt * 16 + quad * 4 + r;
            int g = row0 + m;
            float v0 = acc[mt][0][r], v1 = acc[mt][1][r];
            if (g < NNODES) {
                int n0 = w * 32 + l15, n1 = n0 + 16;
                if (final_layer) {
                    unsigned short a0 = f2h(v0), a1 = f2h(v1);
                    unsigned p0 = (unsigned)a0 | ((unsigned)f2h(v0 - h2f(a0)) << 16);
                    unsigned p1 = (unsigned)a1 | ((unsigned)f2h(v1 - h2f(a1)) << 16);
                    Hpk[(size_t)g * 128 + n0] = p0;
                    Hpk[(size_t)g * 128 + n1] = p1;
                } else {
                    Hhi[(size_t)g * 128 + n0] = f2h(v0);
                    Hhi[(size_t)g * 128 + n1] = f2h(v1);
                }
            }
            float ps = v0 * as0 + v1 * as1;
            float pd = v0 * ad0 + v1 * ad1;
            ps += __shfl_xor(ps, 1); ps += __shfl_xor(ps, 2);
            ps += __shfl_xor(ps, 4); ps += __shfl_xor(ps, 8);
            pd += __shfl_xor(pd, 1); pd += __shfl_xor(pd, 2);
            pd += __shfl_xor(pd, 4); pd += __shfl_xor(pd, 8);
            if (l15 == 0) { eS[w][m] = ps; eD[w][m] = pd; }
        }
    }
    __syncthreads();
    {
        int m = tid >> 1, head = tid & 1;
        int g = row0 + m;
        if (g < NNODES) {
            e_src[g * 2 + head] = eS[head * 2][m] + eS[head * 2 + 1][m];
            e_dst[g * 2 + head] = eD[head * 2][m] + eD[head * 2 + 1][m];
        }
    }
}

// ---------------- hidden-layer aggregation: fp16 h plane (256 B rows) ------
// one wave per dst; lanes 0-31 = edge j, 32-63 = edge j+1; li owns ch 4li..4li+3.
__global__ __launch_bounds__(256) void k_aggregate_h(const unsigned short* __restrict__ Hhi,
                                                     const float* __restrict__ e_src,
                                                     const float* __restrict__ e_dst,
                                                     const int* __restrict__ row_ptr,
                                                     const int* __restrict__ csr_src,
                                                     const float* __restrict__ bias,
                                                     unsigned short* __restrict__ ohi,
                                                     unsigned short* __restrict__ olo) {
    int lane = threadIdx.x & 63;
    int wv   = threadIdx.x >> 6;
    int d    = blockIdx.x * 4 + wv;
    if (d >= NNODES) return;
    int half = lane >> 5;
    int li   = lane & 31;
    int head = li >> 4;
    int c0   = li * 4;
    float ed = e_dst[d * 2 + head];
    int beg = row_ptr[d], end = row_ptr[d + 1];
    f32x4 acc = {0.f, 0.f, 0.f, 0.f};
    float ssum = 0.f;
    int j = beg;
    for (; j + 16 <= end; j += 16) {
        int s[8];
        #pragma unroll
        for (int u = 0; u < 8; u++) s[u] = csr_src[j + 2 * u + half];
        us4 q[8];
        #pragma unroll
        for (int u = 0; u < 8; u++) q[u] = *(const us4*)(Hhi + (size_t)s[u] * 128 + c0);
        float p[8];
        #pragma unroll
        for (int u = 0; u < 8; u++) {
            float t = e_src[s[u] * 2 + head] + ed;
            t = t > 0.f ? t : NEG_SLOPE * t;
            p[u] = __expf(t);
        }
        #pragma unroll
        for (int u = 0; u < 8; u++) {
            acc[0] += p[u] * h2f(q[u][0]);
            acc[1] += p[u] * h2f(q[u][1]);
            acc[2] += p[u] * h2f(q[u][2]);
            acc[3] += p[u] * h2f(q[u][3]);
            ssum   += p[u];
        }
    }
    for (; j < end; j += 2) {
        int idx = j + half;
        bool valid = idx < end;
        int s = csr_src[valid ? idx : end - 1];
        float t = e_src[s * 2 + head] + ed;
        t = t > 0.f ? t : NEG_SLOPE * t;
        float p = valid ? __expf(t) : 0.f;
        us4 q = *(const us4*)(Hhi + (size_t)s * 128 + c0);
        acc[0] += p * h2f(q[0]);
        acc[1] += p * h2f(q[1]);
        acc[2] += p * h2f(q[2]);
        acc[3] += p * h2f(q[3]);
        ssum   += p;
    }
    acc[0] += __shfl_xor(acc[0], 32);
    acc[1] += __shfl_xor(acc[1], 32);
    acc[2] += __shfl_xor(acc[2], 32);
    acc[3] += __shfl_xor(acc[3], 32);
    ssum   += __shfl_xor(ssum,   32);
    if (half == 0) {
        float inv = 1.0f / ssum;
        float4 bv = *(const float4*)(bias + c0);
        float o0 = fmaxf(acc[0] * inv + bv.x, 0.f);
        float o1 = fmaxf(acc[1] * inv + bv.y, 0.f);
        float o2 = fmaxf(acc[2] * inv + bv.z, 0.f);
        float o3 = fmaxf(acc[3] * inv + bv.w, 0.f);
        unsigned short h0 = f2bf(o0), h1 = f2bf(o1), h2 = f2bf(o2), h3 = f2bf(o3);
        *(ushort4*)&ohi[(size_t)d * 128 + c0] = make_ushort4(h0, h1, h2, h3);
        *(ushort4*)&olo[(size_t)d * 128 + c0] =
            make_ushort4(f2bf(o0 - bf2f(h0)), f2bf(o1 - bf2f(h1)),
                         f2bf(o2 - bf2f(h2)), f2bf(o3 - bf2f(h3)));
    }
}

// ---------------- final-layer aggregation: packed fp16 hi|lo (512 B rows) ---
__global__ __launch_bounds__(256) void k_aggregate_f(const unsigned* __restrict__ Hpk,
                                                     const float* __restrict__ e_src,
                                                     const float* __restrict__ e_dst,
                                                     const int* __restrict__ row_ptr,
                                                     const int* __restrict__ csr_src,
                                                     const float* __restrict__ bias,
                                                     float* __restrict__ outf) {
    int lane = threadIdx.x & 63;
    int wv   = threadIdx.x >> 6;
    int d    = blockIdx.x * 4 + wv;
    if (d >= NNODES) return;
    int half = lane >> 5;
    int li   = lane & 31;
    int head = li >> 4;
    int c0   = li * 4;
    float ed = e_dst[d * 2 + head];
    int beg = row_ptr[d], end = row_ptr[d + 1];
    f32x4 acc = {0.f, 0.f, 0.f, 0.f};
    float ssum = 0.f;
    int j = beg;
    for (; j + 16 <= end; j += 16) {
        int s[8];
        #pragma unroll
        for (int u = 0; u < 8; u++) s[u] = csr_src[j + 2 * u + half];
        u32x4 q[8];
        #pragma unroll
        for (int u = 0; u < 8; u++) q[u] = *(const u32x4*)(Hpk + (size_t)s[u] * 128 + c0);
        float p[8];
        #pragma unroll
        for (int u = 0; u < 8; u++) {
            float t = e_src[s[u] * 2 + head] + ed;
            t = t > 0.f ? t : NEG_SLOPE * t;
            p[u] = __expf(t);
        }
        #pragma unroll
        for (int u = 0; u < 8; u++) {
            #pragma unroll
            for (int c = 0; c < 4; c++) {
                float v = h2f((unsigned short)(q[u][c] & 0xffff)) +
                          h2f((unsigned short)(q[u][c] >> 16));
                acc[c] += p[u] * v;
            }
            ssum += p[u];
        }
    }
    for (; j < end; j += 2) {
        int idx = j + half;
        bool valid = idx < end;
        int s = csr_src[valid ? idx : end - 1];
        float t = e_src[s * 2 + head] + ed;
        t = t > 0.f ? t : NEG_SLOPE * t;
        float p = valid ? __expf(t) : 0.f;
        u32x4 q = *(const u32x4*)(Hpk + (size_t)s * 128 + c0);
        #pragma unroll
        for (int c = 0; c < 4; c++) {
            float v = h2f((unsigned short)(q[c] & 0xffff)) +
                      h2f((unsigned short)(q[c] >> 16));
            acc[c] += p * v;
        }
        ssum += p;
    }
    acc[0] += __shfl_xor(acc[0], 32);
    acc[1] += __shfl_xor(acc[1], 32);
    acc[2] += __shfl_xor(acc[2], 32);
    acc[3] += __shfl_xor(acc[3], 32);
    ssum   += __shfl_xor(ssum,   32);
    if (half == 0) {
        float inv = 1.0f / ssum;
        float4 bv = *(const float4*)(bias + c0);
        *(float4*)(outf + (size_t)d * 128 + c0) =
            make_float4(acc[0] * inv + bv.x, acc[1] * inv + bv.y,
                        acc[2] * inv + bv.z, acc[3] * inv + bv.w);
    }
}

// ---------------- host ----------------

extern "C" void kernel_launch(void* const* d_in, const int* in_sizes, int n_in,
                              void* d_out, int out_size, void* d_ws, size_t ws_size,
                              hipStream_t stream) {
    const float* x  = (const float*)d_in[0];
    const int*   ei = (const int*)d_in[1];   // int32 (harness converts int64)

    char* ws = (char*)d_ws;
    size_t off = 0;
    auto alloc = [&](size_t bytes) {
        void* p = ws + off;
        off = (off + bytes + 255) & ~(size_t)255;
        return p;
    };
    int*      count   = (int*)alloc((size_t)NNODES * 4);
    int*      row_ptr = (int*)alloc((size_t)(NNODES + 1) * 4);
    int*      csr     = (int*)alloc((size_t)(NEDGES + NNODES) * 4);
    int*      pos     = (int*)alloc((size_t)NEDGES * 4);
    unsigned* hpk     = (unsigned*)alloc((size_t)NNODES * 128 * 4);  // final: packed fp16 pair
    float*    es      = (float*)alloc((size_t)NNODES * 2 * 4);
    float*    edv     = (float*)alloc((size_t)NNODES * 2 * 4);
    (void)ws_size; (void)in_sizes; (void)n_in; (void)out_size;

    unsigned short* hhi = (unsigned short*)hpk;      // hidden: fp16 plane (aliases hpk)
    unsigned short* hi  = (unsigned short*)d_out;    // act bf16 hi plane
    unsigned short* lo  = hi + (size_t)NNODES * 128; // act bf16 lo plane

    hipMemsetAsync(count, 0, (size_t)NNODES * 4, stream);
    k_count   <<<(NEDGES + 8 * 256 - 1) / (8 * 256), 256, 0, stream>>>(ei, count, pos);
    k_scan    <<<1, 1024, 0, stream>>>(count, row_ptr);
    k_selfloop<<<(NNODES + 255) / 256, 256, 0, stream>>>(row_ptr, csr);
    k_scatter <<<(NEDGES + 4 * 256 - 1) / (4 * 256), 256, 0, stream>>>(ei, row_ptr, pos, csr);
    k_split   <<<(NNODES * 128 / 4 + 255) / 256, 256, 0, stream>>>(x, hi, lo);

    const float* W_h = (const float*)d_in[6];
    const float* ash = (const float*)d_in[7];
    const float* adh = (const float*)d_in[8];
    const float* bh  = (const float*)d_in[9];

    struct Layer { const float *W, *as, *ad, *b; };
    Layer L[4] = {
        { (const float*)d_in[2],  (const float*)d_in[3],  (const float*)d_in[4],  (const float*)d_in[5]  },
        { W_h,              ash,        adh,        bh        },
        { W_h + 128 * 128,  ash + 128,  adh + 128,  bh + 128  },
        { (const float*)d_in[10], (const float*)d_in[11], (const float*)d_in[12], (const float*)d_in[13] },
    };

    const int gemm_blocks = (NNODES + 127) / 128;   // 391
    const int agg_blocks  = (NNODES + 3) / 4;
    for (int l = 0; l < 4; l++) {
        k_gemm_mfma<<<gemm_blocks, 256, 0, stream>>>(hi, lo, L[l].W, L[l].as, L[l].ad,
                                                     hhi, hpk, es, edv, l == 3 ? 1 : 0);
        if (l < 3) {
            k_aggregate_h<<<agg_blocks, 256, 0, stream>>>(hhi, es, edv, row_ptr, csr,
                                                          L[l].b, hi, lo);
        } else {
            k_aggregate_f<<<agg_blocks, 256, 0, stream>>>(hpk, es, edv, row_ptr, csr,
                                                          L[l].b, (float*)d_out);
        }
    }
}

// Round 8
// 712.727 us; speedup vs baseline: 1.8861x; 1.0236x over previous
//
#include <hip/hip_runtime.h>

#define NNODES 50000
#define NEDGES 1600000
#define NEG_SLOPE 0.2f

typedef __attribute__((ext_vector_type(8))) short short8;
typedef __attribute__((ext_vector_type(4))) float f32x4;
typedef __attribute__((ext_vector_type(4))) unsigned short us4;

static __device__ __forceinline__ unsigned short f2bf(float f) {
    unsigned u = __float_as_uint(f);
    unsigned r = u + 0x7FFFu + ((u >> 16) & 1u);   // RNE
    return (unsigned short)(r >> 16);
}
static __device__ __forceinline__ float bf2f(unsigned short h) {
    return __uint_as_float(((unsigned)h) << 16);
}
static __device__ __forceinline__ unsigned short f2h(float f) {
    union { _Float16 x; unsigned short u; } c;
    c.x = (_Float16)f;
    return c.u;
}
static __device__ __forceinline__ float h2f(unsigned short u) {
    union { unsigned short u; _Float16 x; } c;
    c.u = u;
    return (float)c.x;
}

// ---------------- CSR build (edge_index arrives as int32) ----------------

__global__ void k_count(const int* __restrict__ ei, int* __restrict__ count,
                        int* __restrict__ pos) {
    int t = blockIdx.x * blockDim.x + threadIdx.x;
    int stride = gridDim.x * blockDim.x;
    #pragma unroll
    for (int i = 0; i < 8; i++) {
        int e = t + i * stride;
        if (e < NEDGES) pos[e] = atomicAdd(&count[ei[NEDGES + e]], 1);
    }
}

// scan fused with self-loop placement: csr[row_ptr[i]] = i written inline.
__global__ __launch_bounds__(1024) void k_scan(const int* __restrict__ count,
                                               int* __restrict__ row_ptr,
                                               int* __restrict__ csr_src) {
    __shared__ int sums[1024];
    const int per = (NNODES + 1023) / 1024;
    int tid = threadIdx.x;
    int base = tid * per;
    int local = 0;
    for (int i = 0; i < per; i++) {
        int idx = base + i;
        if (idx < NNODES) local += count[idx] + 1;   // +1 = self loop
    }
    sums[tid] = local;
    __syncthreads();
    for (int off = 1; off < 1024; off <<= 1) {
        int v = 0;
        if (tid >= off) v = sums[tid - off];
        __syncthreads();
        sums[tid] += v;
        __syncthreads();
    }
    int run = sums[tid] - local;
    for (int i = 0; i < per; i++) {
        int idx = base + i;
        if (idx < NNODES) {
            row_ptr[idx] = run;
            csr_src[run] = idx;          // self-loop slot 0 of segment
            run += count[idx] + 1;
        }
    }
    if (tid == 1023) row_ptr[NNODES] = sums[1023];
}

__global__ void k_scatter(const int* __restrict__ ei, const int* __restrict__ row_ptr,
                          const int* __restrict__ pos, int* __restrict__ csr_src) {
    int t = blockIdx.x * blockDim.x + threadIdx.x;
    int stride = gridDim.x * blockDim.x;
    #pragma unroll
    for (int i = 0; i < 4; i++) {
        int e = t + i * stride;
        if (e < NEDGES) {
            int s = ei[e];
            int d = ei[NEDGES + e];
            __builtin_nontemporal_store(s, &csr_src[row_ptr[d] + 1 + pos[e]]);
        }
    }
}

// ---------------- layer-0 input split: x -> bf16 hi/lo planes ----------------

__global__ void k_split(const float* __restrict__ x, unsigned short* __restrict__ hi,
                        unsigned short* __restrict__ lo) {
    int i = blockIdx.x * blockDim.x + threadIdx.x;
    if (i >= NNODES * 128 / 4) return;
    float4 v = *(const float4*)(x + (size_t)i * 4);
    unsigned short h0 = f2bf(v.x), h1 = f2bf(v.y), h2 = f2bf(v.z), h3 = f2bf(v.w);
    *(ushort4*)(hi + (size_t)i * 4) = make_ushort4(h0, h1, h2, h3);
    *(ushort4*)(lo + (size_t)i * 4) =
        make_ushort4(f2bf(v.x - bf2f(h0)), f2bf(v.y - bf2f(h1)),
                     f2bf(v.z - bf2f(h2)), f2bf(v.w - bf2f(h3)));
}

// ---------------- MFMA GEMM + attention-coefficient epilogue ----------------
// C = X*W via split-bf16: Xh*Wh + Xh*Wl + Xl*Wh (err ~2^-17 rel).
// Epilogue: h written as a single fp16 plane (256 B rows) for the gather wall;
// attention dots e_src/e_dst computed from the fp32 accumulators (exact path).
__global__ __launch_bounds__(256, 2) void k_gemm_mfma(
        const unsigned short* __restrict__ Ahi, const unsigned short* __restrict__ Alo,
        const float* __restrict__ W,
        const float* __restrict__ a_src, const float* __restrict__ a_dst,
        unsigned short* __restrict__ Hh,
        float* __restrict__ e_src, float* __restrict__ e_dst)
{
    __shared__ __align__(16) short sAhi[128 * 128];   // 32 KB
    __shared__ __align__(16) short sAlo[128 * 128];   // 32 KB
    __shared__ float eS[4][128];
    __shared__ float eD[4][128];

    const int tid  = threadIdx.x;
    const int lane = tid & 63;
    const int w    = tid >> 6;
    const int l15  = lane & 15;
    const int quad = lane >> 4;
    const int row0 = blockIdx.x * 128;

    short8 Bh[2][4], Bl[2][4];
    for (int nt = 0; nt < 2; nt++) {
        int n = w * 32 + nt * 16 + l15;
        for (int ks = 0; ks < 4; ks++) {
            short8 bh, bl;
            #pragma unroll
            for (int j = 0; j < 8; j++) {
                float wv = W[(size_t)(ks * 32 + quad * 8 + j) * 128 + n];
                unsigned short h = f2bf(wv);
                bh[j] = (short)h;
                bl[j] = (short)f2bf(wv - bf2f(h));
            }
            Bh[nt][ks] = bh; Bl[nt][ks] = bl;
        }
    }

    for (int i = tid; i < 2048; i += 256) {
        int m  = i >> 4;
        int kc = i & 15;
        int g  = row0 + m; if (g > NNODES - 1) g = NNODES - 1;
        int cp = kc ^ (m & 15);
        short8 vh = *(const short8*)(Ahi + (size_t)g * 128 + kc * 8);
        short8 vl = *(const short8*)(Alo + (size_t)g * 128 + kc * 8);
        *(short8*)&sAhi[m * 128 + cp * 8] = vh;
        *(short8*)&sAlo[m * 128 + cp * 8] = vl;
    }
    __syncthreads();

    f32x4 zero = {0.f, 0.f, 0.f, 0.f};
    f32x4 acc[8][2];
    #pragma unroll
    for (int mt = 0; mt < 8; mt++) { acc[mt][0] = zero; acc[mt][1] = zero; }

    #pragma unroll
    for (int mt = 0; mt < 8; mt++) {
        int m = mt * 16 + l15;
        #pragma unroll
        for (int ks = 0; ks < 4; ks++) {
            int kc = ks * 4 + quad;
            int cp = kc ^ l15;
            short8 ah = *(const short8*)&sAhi[m * 128 + cp * 8];
            short8 al = *(const short8*)&sAlo[m * 128 + cp * 8];
            #pragma unroll
            for (int nt = 0; nt < 2; nt++) {
                acc[mt][nt] = __builtin_amdgcn_mfma_f32_16x16x32_bf16(ah, Bh[nt][ks], acc[mt][nt], 0, 0, 0);
                acc[mt][nt] = __builtin_amdgcn_mfma_f32_16x16x32_bf16(al, Bh[nt][ks], acc[mt][nt], 0, 0, 0);
                acc[mt][nt] = __builtin_amdgcn_mfma_f32_16x16x32_bf16(ah, Bl[nt][ks], acc[mt][nt], 0, 0, 0);
            }
        }
    }

    float as0 = a_src[w * 32 + l15],      ad0 = a_dst[w * 32 + l15];
    float as1 = a_src[w * 32 + 16 + l15], ad1 = a_dst[w * 32 + 16 + l15];
    #pragma unroll
    for (int mt = 0; mt < 8; mt++) {
        #pragma unroll
        for (int r = 0; r < 4; r++) {
            int m = mt * 16 + quad * 4 + r;
            int g = row0 + m;
            float v0 = acc[mt][0][r], v1 = acc[mt][1][r];
            if (g < NNODES) {
                int n0 = w * 32 + l15;
                Hh[(size_t)g * 128 + n0]      = f2h(v0);
                Hh[(size_t)g * 128 + n0 + 16] = f2h(v1);
            }
            float ps = v0 * as0 + v1 * as1;
            float pd = v0 * ad0 + v1 * ad1;
            ps += __shfl_xor(ps, 1); ps += __shfl_xor(ps, 2);
            ps += __shfl_xor(ps, 4); ps += __shfl_xor(ps, 8);
            pd += __shfl_xor(pd, 1); pd += __shfl_xor(pd, 2);
            pd += __shfl_xor(pd, 4); pd += __shfl_xor(pd, 8);
            if (l15 == 0) { eS[w][m] = ps; eD[w][m] = pd; }
        }
    }
    __syncthreads();
    {
        int m = tid >> 1, head = tid & 1;
        int g = row0 + m;
        if (g < NNODES) {
            e_src[g * 2 + head] = eS[head * 2][m] + eS[head * 2 + 1][m];
            e_dst[g * 2 + head] = eD[head * 2][m] + eD[head * 2 + 1][m];
        }
    }
}

// ---------------- hidden-layer aggregation: fp16 h plane (256 B rows) ------
// one wave per dst; lanes 0-31 = edge j, 32-63 = edge j+1; li owns ch 4li..4li+3.
__global__ __launch_bounds__(256) void k_aggregate_h(const unsigned short* __restrict__ Hh,
                                                     const float* __restrict__ e_src,
                                                     const float* __restrict__ e_dst,
                                                     const int* __restrict__ row_ptr,
                                                     const int* __restrict__ csr_src,
                                                     const float* __restrict__ bias,
                                                     unsigned short* __restrict__ ohi,
                                                     unsigned short* __restrict__ olo) {
    int lane = threadIdx.x & 63;
    int wv   = threadIdx.x >> 6;
    int d    = blockIdx.x * 4 + wv;
    if (d >= NNODES) return;
    int half = lane >> 5;
    int li   = lane & 31;
    int head = li >> 4;
    int c0   = li * 4;
    float ed = e_dst[d * 2 + head];
    int beg = row_ptr[d], end = row_ptr[d + 1];
    f32x4 acc = {0.f, 0.f, 0.f, 0.f};
    float ssum = 0.f;
    int j = beg;
    for (; j + 16 <= end; j += 16) {
        int s[8];
        #pragma unroll
        for (int u = 0; u < 8; u++) s[u] = csr_src[j + 2 * u + half];
        us4 q[8];
        #pragma unroll
        for (int u = 0; u < 8; u++) q[u] = *(const us4*)(Hh + (size_t)s[u] * 128 + c0);
        float p[8];
        #pragma unroll
        for (int u = 0; u < 8; u++) {
            float t = e_src[s[u] * 2 + head] + ed;
            t = t > 0.f ? t : NEG_SLOPE * t;
            p[u] = __expf(t);
        }
        #pragma unroll
        for (int u = 0; u < 8; u++) {
            acc[0] += p[u] * h2f(q[u][0]);
            acc[1] += p[u] * h2f(q[u][1]);
            acc[2] += p[u] * h2f(q[u][2]);
            acc[3] += p[u] * h2f(q[u][3]);
            ssum   += p[u];
        }
    }
    for (; j < end; j += 2) {
        int idx = j + half;
        bool valid = idx < end;
        int s = csr_src[valid ? idx : end - 1];
        float t = e_src[s * 2 + head] + ed;
        t = t > 0.f ? t : NEG_SLOPE * t;
        float p = valid ? __expf(t) : 0.f;
        us4 q = *(const us4*)(Hh + (size_t)s * 128 + c0);
        acc[0] += p * h2f(q[0]);
        acc[1] += p * h2f(q[1]);
        acc[2] += p * h2f(q[2]);
        acc[3] += p * h2f(q[3]);
        ssum   += p;
    }
    acc[0] += __shfl_xor(acc[0], 32);
    acc[1] += __shfl_xor(acc[1], 32);
    acc[2] += __shfl_xor(acc[2], 32);
    acc[3] += __shfl_xor(acc[3], 32);
    ssum   += __shfl_xor(ssum,   32);
    if (half == 0) {
        float inv = 1.0f / ssum;
        float4 bv = *(const float4*)(bias + c0);
        float o0 = fmaxf(acc[0] * inv + bv.x, 0.f);
        float o1 = fmaxf(acc[1] * inv + bv.y, 0.f);
        float o2 = fmaxf(acc[2] * inv + bv.z, 0.f);
        float o3 = fmaxf(acc[3] * inv + bv.w, 0.f);
        unsigned short h0 = f2bf(o0), h1 = f2bf(o1), h2 = f2bf(o2), h3 = f2bf(o3);
        *(ushort4*)&ohi[(size_t)d * 128 + c0] = make_ushort4(h0, h1, h2, h3);
        *(ushort4*)&olo[(size_t)d * 128 + c0] =
            make_ushort4(f2bf(o0 - bf2f(h0)), f2bf(o1 - bf2f(h1)),
                         f2bf(o2 - bf2f(h2)), f2bf(o3 - bf2f(h3)));
    }
}

// ---------------- final-layer aggregation: fp16 h plane, fp32 output --------
__global__ __launch_bounds__(256) void k_aggregate_f(const unsigned short* __restrict__ Hh,
                                                     const float* __restrict__ e_src,
                                                     const float* __restrict__ e_dst,
                                                     const int* __restrict__ row_ptr,
                                                     const int* __restrict__ csr_src,
                                                     const float* __restrict__ bias,
                                                     float* __restrict__ outf) {
    int lane = threadIdx.x & 63;
    int wv   = threadIdx.x >> 6;
    int d    = blockIdx.x * 4 + wv;
    if (d >= NNODES) return;
    int half = lane >> 5;
    int li   = lane & 31;
    int head = li >> 4;
    int c0   = li * 4;
    float ed = e_dst[d * 2 + head];
    int beg = row_ptr[d], end = row_ptr[d + 1];
    f32x4 acc = {0.f, 0.f, 0.f, 0.f};
    float ssum = 0.f;
    int j = beg;
    for (; j + 16 <= end; j += 16) {
        int s[8];
        #pragma unroll
        for (int u = 0; u < 8; u++) s[u] = csr_src[j + 2 * u + half];
        us4 q[8];
        #pragma unroll
        for (int u = 0; u < 8; u++) q[u] = *(const us4*)(Hh + (size_t)s[u] * 128 + c0);
        float p[8];
        #pragma unroll
        for (int u = 0; u < 8; u++) {
            float t = e_src[s[u] * 2 + head] + ed;
            t = t > 0.f ? t : NEG_SLOPE * t;
            p[u] = __expf(t);
        }
        #pragma unroll
        for (int u = 0; u < 8; u++) {
            acc[0] += p[u] * h2f(q[u][0]);
            acc[1] += p[u] * h2f(q[u][1]);
            acc[2] += p[u] * h2f(q[u][2]);
            acc[3] += p[u] * h2f(q[u][3]);
            ssum   += p[u];
        }
    }
    for (; j < end; j += 2) {
        int idx = j + half;
        bool valid = idx < end;
        int s = csr_src[valid ? idx : end - 1];
        float t = e_src[s * 2 + head] + ed;
        t = t > 0.f ? t : NEG_SLOPE * t;
        float p = valid ? __expf(t) : 0.f;
        us4 q = *(const us4*)(Hh + (size_t)s * 128 + c0);
        acc[0] += p * h2f(q[0]);
        acc[1] += p * h2f(q[1]);
        acc[2] += p * h2f(q[2]);
        acc[3] += p * h2f(q[3]);
        ssum   += p;
    }
    acc[0] += __shfl_xor(acc[0], 32);
    acc[1] += __shfl_xor(acc[1], 32);
    acc[2] += __shfl_xor(acc[2], 32);
    acc[3] += __shfl_xor(acc[3], 32);
    ssum   += __shfl_xor(ssum,   32);
    if (half == 0) {
        float inv = 1.0f / ssum;
        float4 bv = *(const float4*)(bias + c0);
        *(float4*)(outf + (size_t)d * 128 + c0) =
            make_float4(acc[0] * inv + bv.x, acc[1] * inv + bv.y,
                        acc[2] * inv + bv.z, acc[3] * inv + bv.w);
    }
}

// ---------------- host ----------------

extern "C" void kernel_launch(void* const* d_in, const int* in_sizes, int n_in,
                              void* d_out, int out_size, void* d_ws, size_t ws_size,
                              hipStream_t stream) {
    const float* x  = (const float*)d_in[0];
    const int*   ei = (const int*)d_in[1];   // int32 (harness converts int64)

    char* ws = (char*)d_ws;
    size_t off = 0;
    auto alloc = [&](size_t bytes) {
        void* p = ws + off;
        off = (off + bytes + 255) & ~(size_t)255;
        return p;
    };
    int*            count   = (int*)alloc((size_t)NNODES * 4);
    int*            row_ptr = (int*)alloc((size_t)(NNODES + 1) * 4);
    int*            csr     = (int*)alloc((size_t)(NEDGES + NNODES) * 4);
    int*            pos     = (int*)alloc((size_t)NEDGES * 4);
    unsigned short* hh      = (unsigned short*)alloc((size_t)NNODES * 128 * 2);  // fp16 h plane
    float*          es      = (float*)alloc((size_t)NNODES * 2 * 4);
    float*          edv     = (float*)alloc((size_t)NNODES * 2 * 4);
    (void)ws_size; (void)in_sizes; (void)n_in; (void)out_size;

    unsigned short* hi = (unsigned short*)d_out;     // act bf16 hi plane
    unsigned short* lo = hi + (size_t)NNODES * 128;  // act bf16 lo plane

    hipMemsetAsync(count, 0, (size_t)NNODES * 4, stream);
    k_count  <<<(NEDGES + 8 * 256 - 1) / (8 * 256), 256, 0, stream>>>(ei, count, pos);
    k_scan   <<<1, 1024, 0, stream>>>(count, row_ptr, csr);
    k_scatter<<<(NEDGES + 4 * 256 - 1) / (4 * 256), 256, 0, stream>>>(ei, row_ptr, pos, csr);
    k_split  <<<(NNODES * 128 / 4 + 255) / 256, 256, 0, stream>>>(x, hi, lo);

    const float* W_h = (const float*)d_in[6];
    const float* ash = (const float*)d_in[7];
    const float* adh = (const float*)d_in[8];
    const float* bh  = (const float*)d_in[9];

    struct Layer { const float *W, *as, *ad, *b; };
    Layer L[4] = {
        { (const float*)d_in[2],  (const float*)d_in[3],  (const float*)d_in[4],  (const float*)d_in[5]  },
        { W_h,              ash,        adh,        bh        },
        { W_h + 128 * 128,  ash + 128,  adh + 128,  bh + 128  },
        { (const float*)d_in[10], (const float*)d_in[11], (const float*)d_in[12], (const float*)d_in[13] },
    };

    const int gemm_blocks = (NNODES + 127) / 128;   // 391
    const int agg_blocks  = (NNODES + 3) / 4;
    for (int l = 0; l < 4; l++) {
        k_gemm_mfma<<<gemm_blocks, 256, 0, stream>>>(hi, lo, L[l].W, L[l].as, L[l].ad,
                                                     hh, es, edv);
        if (l < 3) {
            k_aggregate_h<<<agg_blocks, 256, 0, stream>>>(hh, es, edv, row_ptr, csr,
                                                          L[l].b, hi, lo);
        } else {
            k_aggregate_f<<<agg_blocks, 256, 0, stream>>>(hh, es, edv, row_ptr, csr,
                                                          L[l].b, (float*)d_out);
        }
    }
}

// Round 9
// 596.436 us; speedup vs baseline: 2.2539x; 1.1950x over previous
//
#include <hip/hip_runtime.h>

#define NNODES 50000
#define NEDGES 1600000
#define NEG_SLOPE 0.2f

#define SCAN_NB 256
#define SCAN_CH 196   // ceil(50000/256); 256*196 = 50176 >= 50000

typedef __attribute__((ext_vector_type(8))) short short8;
typedef __attribute__((ext_vector_type(4))) float f32x4;
typedef __attribute__((ext_vector_type(4))) unsigned short us4;

static __device__ __forceinline__ unsigned short f2bf(float f) {
    unsigned u = __float_as_uint(f);
    unsigned r = u + 0x7FFFu + ((u >> 16) & 1u);   // RNE
    return (unsigned short)(r >> 16);
}
static __device__ __forceinline__ float bf2f(unsigned short h) {
    return __uint_as_float(((unsigned)h) << 16);
}
static __device__ __forceinline__ unsigned short f2h(float f) {
    union { _Float16 x; unsigned short u; } c;
    c.x = (_Float16)f;
    return c.u;
}
static __device__ __forceinline__ float h2f(unsigned short u) {
    union { unsigned short u; _Float16 x; } c;
    c.u = u;
    return (float)c.x;
}

// ---------------- CSR build (edge_index arrives as int32) ----------------

__global__ void k_count(const int* __restrict__ ei, int* __restrict__ count,
                        int* __restrict__ pos) {
    int t = blockIdx.x * blockDim.x + threadIdx.x;
    int stride = gridDim.x * blockDim.x;
    #pragma unroll
    for (int i = 0; i < 8; i++) {
        int e = t + i * stride;
        if (e < NEDGES) pos[e] = atomicAdd(&count[ei[NEDGES + e]], 1);
    }
}

// ---- hierarchical parallel scan (replaces the 127us single-block scan) ----
// phase 1: per-block chunk sums
__global__ __launch_bounds__(256) void k_bsum(const int* __restrict__ count,
                                              int* __restrict__ bsum) {
    __shared__ int red[4];
    int t = threadIdx.x, b = blockIdx.x;
    int idx = b * SCAN_CH + t;
    int v = (t < SCAN_CH && idx < NNODES) ? count[idx] + 1 : 0;   // +1 self loop
    #pragma unroll
    for (int m = 1; m <= 32; m <<= 1) v += __shfl_xor(v, m);
    if ((t & 63) == 0) red[t >> 6] = v;
    __syncthreads();
    if (t == 0) bsum[b] = red[0] + red[1] + red[2] + red[3];
}

// phase 2: scan the 256 block sums (one tiny block)
__global__ __launch_bounds__(256) void k_bscan(const int* __restrict__ bsum,
                                               int* __restrict__ boff,
                                               int* __restrict__ row_ptr) {
    __shared__ int s[256];
    int t = threadIdx.x;
    int v = bsum[t];
    s[t] = v;
    __syncthreads();
    for (int off = 1; off < 256; off <<= 1) {
        int u = (t >= off) ? s[t - off] : 0;
        __syncthreads();
        s[t] += u;
        __syncthreads();
    }
    boff[t] = s[t] - v;                      // exclusive block offset
    if (t == 255) row_ptr[NNODES] = s[255];  // total = E + N
}

// phase 3: intra-chunk prefix + row_ptr + self-loop placement (parallel)
__global__ __launch_bounds__(256) void k_rowptr(const int* __restrict__ count,
                                                const int* __restrict__ boff,
                                                int* __restrict__ row_ptr,
                                                int* __restrict__ csr_src) {
    __shared__ int s[256];
    int t = threadIdx.x, b = blockIdx.x;
    int idx = b * SCAN_CH + t;
    bool valid = (t < SCAN_CH && idx < NNODES);
    int v = valid ? count[idx] + 1 : 0;
    s[t] = v;
    __syncthreads();
    for (int off = 1; off < 256; off <<= 1) {
        int u = (t >= off) ? s[t - off] : 0;
        __syncthreads();
        s[t] += u;
        __syncthreads();
    }
    if (valid) {
        int run = boff[b] + s[t] - v;
        row_ptr[idx] = run;
        csr_src[run] = idx;                  // self-loop slot 0 of segment
    }
}

__global__ void k_scatter(const int* __restrict__ ei, const int* __restrict__ row_ptr,
                          const int* __restrict__ pos, int* __restrict__ csr_src) {
    int t = blockIdx.x * blockDim.x + threadIdx.x;
    int stride = gridDim.x * blockDim.x;
    #pragma unroll
    for (int i = 0; i < 4; i++) {
        int e = t + i * stride;
        if (e < NEDGES) {
            int s = ei[e];
            int d = ei[NEDGES + e];
            __builtin_nontemporal_store(s, &csr_src[row_ptr[d] + 1 + pos[e]]);
        }
    }
}

// ---------------- layer-0 input split: x -> bf16 hi/lo planes ----------------

__global__ void k_split(const float* __restrict__ x, unsigned short* __restrict__ hi,
                        unsigned short* __restrict__ lo) {
    int i = blockIdx.x * blockDim.x + threadIdx.x;
    if (i >= NNODES * 128 / 4) return;
    float4 v = *(const float4*)(x + (size_t)i * 4);
    unsigned short h0 = f2bf(v.x), h1 = f2bf(v.y), h2 = f2bf(v.z), h3 = f2bf(v.w);
    *(ushort4*)(hi + (size_t)i * 4) = make_ushort4(h0, h1, h2, h3);
    *(ushort4*)(lo + (size_t)i * 4) =
        make_ushort4(f2bf(v.x - bf2f(h0)), f2bf(v.y - bf2f(h1)),
                     f2bf(v.z - bf2f(h2)), f2bf(v.w - bf2f(h3)));
}

// ---------------- MFMA GEMM + attention-coefficient epilogue ----------------
// C = X*W via split-bf16: Xh*Wh + Xh*Wl + Xl*Wh (err ~2^-17 rel).
// Epilogue: h written as fp16 plane (256 B rows) for the gather wall;
// attention dots e_src/e_dst from the fp32 accumulators (exact path).
__global__ __launch_bounds__(256, 2) void k_gemm_mfma(
        const unsigned short* __restrict__ Ahi, const unsigned short* __restrict__ Alo,
        const float* __restrict__ W,
        const float* __restrict__ a_src, const float* __restrict__ a_dst,
        unsigned short* __restrict__ Hh,
        float* __restrict__ e_src, float* __restrict__ e_dst)
{
    __shared__ __align__(16) short sAhi[128 * 128];   // 32 KB
    __shared__ __align__(16) short sAlo[128 * 128];   // 32 KB
    __shared__ float eS[4][128];
    __shared__ float eD[4][128];

    const int tid  = threadIdx.x;
    const int lane = tid & 63;
    const int w    = tid >> 6;
    const int l15  = lane & 15;
    const int quad = lane >> 4;
    const int row0 = blockIdx.x * 128;

    short8 Bh[2][4], Bl[2][4];
    for (int nt = 0; nt < 2; nt++) {
        int n = w * 32 + nt * 16 + l15;
        for (int ks = 0; ks < 4; ks++) {
            short8 bh, bl;
            #pragma unroll
            for (int j = 0; j < 8; j++) {
                float wv = W[(size_t)(ks * 32 + quad * 8 + j) * 128 + n];
                unsigned short h = f2bf(wv);
                bh[j] = (short)h;
                bl[j] = (short)f2bf(wv - bf2f(h));
            }
            Bh[nt][ks] = bh; Bl[nt][ks] = bl;
        }
    }

    for (int i = tid; i < 2048; i += 256) {
        int m  = i >> 4;
        int kc = i & 15;
        int g  = row0 + m; if (g > NNODES - 1) g = NNODES - 1;
        int cp = kc ^ (m & 15);
        short8 vh = *(const short8*)(Ahi + (size_t)g * 128 + kc * 8);
        short8 vl = *(const short8*)(Alo + (size_t)g * 128 + kc * 8);
        *(short8*)&sAhi[m * 128 + cp * 8] = vh;
        *(short8*)&sAlo[m * 128 + cp * 8] = vl;
    }
    __syncthreads();

    f32x4 zero = {0.f, 0.f, 0.f, 0.f};
    f32x4 acc[8][2];
    #pragma unroll
    for (int mt = 0; mt < 8; mt++) { acc[mt][0] = zero; acc[mt][1] = zero; }

    #pragma unroll
    for (int mt = 0; mt < 8; mt++) {
        int m = mt * 16 + l15;
        #pragma unroll
        for (int ks = 0; ks < 4; ks++) {
            int kc = ks * 4 + quad;
            int cp = kc ^ l15;
            short8 ah = *(const short8*)&sAhi[m * 128 + cp * 8];
            short8 al = *(const short8*)&sAlo[m * 128 + cp * 8];
            #pragma unroll
            for (int nt = 0; nt < 2; nt++) {
                acc[mt][nt] = __builtin_amdgcn_mfma_f32_16x16x32_bf16(ah, Bh[nt][ks], acc[mt][nt], 0, 0, 0);
                acc[mt][nt] = __builtin_amdgcn_mfma_f32_16x16x32_bf16(al, Bh[nt][ks], acc[mt][nt], 0, 0, 0);
                acc[mt][nt] = __builtin_amdgcn_mfma_f32_16x16x32_bf16(ah, Bl[nt][ks], acc[mt][nt], 0, 0, 0);
            }
        }
    }

    float as0 = a_src[w * 32 + l15],      ad0 = a_dst[w * 32 + l15];
    float as1 = a_src[w * 32 + 16 + l15], ad1 = a_dst[w * 32 + 16 + l15];
    #pragma unroll
    for (int mt = 0; mt < 8; mt++) {
        #pragma unroll
        for (int r = 0; r < 4; r++) {
            int m = mt * 16 + quad * 4 + r;
            int g = row0 + m;
            float v0 = acc[mt][0][r], v1 = acc[mt][1][r];
            if (g < NNODES) {
                int n0 = w * 32 + l15;
                Hh[(size_t)g * 128 + n0]      = f2h(v0);
                Hh[(size_t)g * 128 + n0 + 16] = f2h(v1);
            }
            float ps = v0 * as0 + v1 * as1;
            float pd = v0 * ad0 + v1 * ad1;
            ps += __shfl_xor(ps, 1); ps += __shfl_xor(ps, 2);
            ps += __shfl_xor(ps, 4); ps += __shfl_xor(ps, 8);
            pd += __shfl_xor(pd, 1); pd += __shfl_xor(pd, 2);
            pd += __shfl_xor(pd, 4); pd += __shfl_xor(pd, 8);
            if (l15 == 0) { eS[w][m] = ps; eD[w][m] = pd; }
        }
    }
    __syncthreads();
    {
        int m = tid >> 1, head = tid & 1;
        int g = row0 + m;
        if (g < NNODES) {
            e_src[g * 2 + head] = eS[head * 2][m] + eS[head * 2 + 1][m];
            e_dst[g * 2 + head] = eD[head * 2][m] + eD[head * 2 + 1][m];
        }
    }
}

// ---------------- hidden-layer aggregation: fp16 h plane (256 B rows) ------
__global__ __launch_bounds__(256) void k_aggregate_h(const unsigned short* __restrict__ Hh,
                                                     const float* __restrict__ e_src,
                                                     const float* __restrict__ e_dst,
                                                     const int* __restrict__ row_ptr,
                                                     const int* __restrict__ csr_src,
                                                     const float* __restrict__ bias,
                                                     unsigned short* __restrict__ ohi,
                                                     unsigned short* __restrict__ olo) {
    int lane = threadIdx.x & 63;
    int wv   = threadIdx.x >> 6;
    int d    = blockIdx.x * 4 + wv;
    if (d >= NNODES) return;
    int half = lane >> 5;
    int li   = lane & 31;
    int head = li >> 4;
    int c0   = li * 4;
    float ed = e_dst[d * 2 + head];
    int beg = row_ptr[d], end = row_ptr[d + 1];
    f32x4 acc = {0.f, 0.f, 0.f, 0.f};
    float ssum = 0.f;
    int j = beg;
    for (; j + 16 <= end; j += 16) {
        int s[8];
        #pragma unroll
        for (int u = 0; u < 8; u++) s[u] = csr_src[j + 2 * u + half];
        us4 q[8];
        #pragma unroll
        for (int u = 0; u < 8; u++) q[u] = *(const us4*)(Hh + (size_t)s[u] * 128 + c0);
        float p[8];
        #pragma unroll
        for (int u = 0; u < 8; u++) {
            float t = e_src[s[u] * 2 + head] + ed;
            t = t > 0.f ? t : NEG_SLOPE * t;
            p[u] = __expf(t);
        }
        #pragma unroll
        for (int u = 0; u < 8; u++) {
            acc[0] += p[u] * h2f(q[u][0]);
            acc[1] += p[u] * h2f(q[u][1]);
            acc[2] += p[u] * h2f(q[u][2]);
            acc[3] += p[u] * h2f(q[u][3]);
            ssum   += p[u];
        }
    }
    for (; j < end; j += 2) {
        int idx = j + half;
        bool valid = idx < end;
        int s = csr_src[valid ? idx : end - 1];
        float t = e_src[s * 2 + head] + ed;
        t = t > 0.f ? t : NEG_SLOPE * t;
        float p = valid ? __expf(t) : 0.f;
        us4 q = *(const us4*)(Hh + (size_t)s * 128 + c0);
        acc[0] += p * h2f(q[0]);
        acc[1] += p * h2f(q[1]);
        acc[2] += p * h2f(q[2]);
        acc[3] += p * h2f(q[3]);
        ssum   += p;
    }
    acc[0] += __shfl_xor(acc[0], 32);
    acc[1] += __shfl_xor(acc[1], 32);
    acc[2] += __shfl_xor(acc[2], 32);
    acc[3] += __shfl_xor(acc[3], 32);
    ssum   += __shfl_xor(ssum,   32);
    if (half == 0) {
        float inv = 1.0f / ssum;
        float4 bv = *(const float4*)(bias + c0);
        float o0 = fmaxf(acc[0] * inv + bv.x, 0.f);
        float o1 = fmaxf(acc[1] * inv + bv.y, 0.f);
        float o2 = fmaxf(acc[2] * inv + bv.z, 0.f);
        float o3 = fmaxf(acc[3] * inv + bv.w, 0.f);
        unsigned short h0 = f2bf(o0), h1 = f2bf(o1), h2 = f2bf(o2), h3 = f2bf(o3);
        *(ushort4*)&ohi[(size_t)d * 128 + c0] = make_ushort4(h0, h1, h2, h3);
        *(ushort4*)&olo[(size_t)d * 128 + c0] =
            make_ushort4(f2bf(o0 - bf2f(h0)), f2bf(o1 - bf2f(h1)),
                         f2bf(o2 - bf2f(h2)), f2bf(o3 - bf2f(h3)));
    }
}

// ---------------- final-layer aggregation: fp16 h plane, fp32 output --------
__global__ __launch_bounds__(256) void k_aggregate_f(const unsigned short* __restrict__ Hh,
                                                     const float* __restrict__ e_src,
                                                     const float* __restrict__ e_dst,
                                                     const int* __restrict__ row_ptr,
                                                     const int* __restrict__ csr_src,
                                                     const float* __restrict__ bias,
                                                     float* __restrict__ outf) {
    int lane = threadIdx.x & 63;
    int wv   = threadIdx.x >> 6;
    int d    = blockIdx.x * 4 + wv;
    if (d >= NNODES) return;
    int half = lane >> 5;
    int li   = lane & 31;
    int head = li >> 4;
    int c0   = li * 4;
    float ed = e_dst[d * 2 + head];
    int beg = row_ptr[d], end = row_ptr[d + 1];
    f32x4 acc = {0.f, 0.f, 0.f, 0.f};
    float ssum = 0.f;
    int j = beg;
    for (; j + 16 <= end; j += 16) {
        int s[8];
        #pragma unroll
        for (int u = 0; u < 8; u++) s[u] = csr_src[j + 2 * u + half];
        us4 q[8];
        #pragma unroll
        for (int u = 0; u < 8; u++) q[u] = *(const us4*)(Hh + (size_t)s[u] * 128 + c0);
        float p[8];
        #pragma unroll
        for (int u = 0; u < 8; u++) {
            float t = e_src[s[u] * 2 + head] + ed;
            t = t > 0.f ? t : NEG_SLOPE * t;
            p[u] = __expf(t);
        }
        #pragma unroll
        for (int u = 0; u < 8; u++) {
            acc[0] += p[u] * h2f(q[u][0]);
            acc[1] += p[u] * h2f(q[u][1]);
            acc[2] += p[u] * h2f(q[u][2]);
            acc[3] += p[u] * h2f(q[u][3]);
            ssum   += p[u];
        }
    }
    for (; j < end; j += 2) {
        int idx = j + half;
        bool valid = idx < end;
        int s = csr_src[valid ? idx : end - 1];
        float t = e_src[s * 2 + head] + ed;
        t = t > 0.f ? t : NEG_SLOPE * t;
        float p = valid ? __expf(t) : 0.f;
        us4 q = *(const us4*)(Hh + (size_t)s * 128 + c0);
        acc[0] += p * h2f(q[0]);
        acc[1] += p * h2f(q[1]);
        acc[2] += p * h2f(q[2]);
        acc[3] += p * h2f(q[3]);
        ssum   += p;
    }
    acc[0] += __shfl_xor(acc[0], 32);
    acc[1] += __shfl_xor(acc[1], 32);
    acc[2] += __shfl_xor(acc[2], 32);
    acc[3] += __shfl_xor(acc[3], 32);
    ssum   += __shfl_xor(ssum,   32);
    if (half == 0) {
        float inv = 1.0f / ssum;
        float4 bv = *(const float4*)(bias + c0);
        *(float4*)(outf + (size_t)d * 128 + c0) =
            make_float4(acc[0] * inv + bv.x, acc[1] * inv + bv.y,
                        acc[2] * inv + bv.z, acc[3] * inv + bv.w);
    }
}

// ---------------- host ----------------

extern "C" void kernel_launch(void* const* d_in, const int* in_sizes, int n_in,
                              void* d_out, int out_size, void* d_ws, size_t ws_size,
                              hipStream_t stream) {
    const float* x  = (const float*)d_in[0];
    const int*   ei = (const int*)d_in[1];   // int32 (harness converts int64)

    char* ws = (char*)d_ws;
    size_t off = 0;
    auto alloc = [&](size_t bytes) {
        void* p = ws + off;
        off = (off + bytes + 255) & ~(size_t)255;
        return p;
    };
    int*            count   = (int*)alloc((size_t)NNODES * 4);
    int*            row_ptr = (int*)alloc((size_t)(NNODES + 1) * 4);
    int*            csr     = (int*)alloc((size_t)(NEDGES + NNODES) * 4);
    int*            pos     = (int*)alloc((size_t)NEDGES * 4);
    int*            bsum    = (int*)alloc((size_t)SCAN_NB * 4);
    int*            boff    = (int*)alloc((size_t)SCAN_NB * 4);
    unsigned short* hh      = (unsigned short*)alloc((size_t)NNODES * 128 * 2);  // fp16 h plane
    float*          es      = (float*)alloc((size_t)NNODES * 2 * 4);
    float*          edv     = (float*)alloc((size_t)NNODES * 2 * 4);
    (void)ws_size; (void)in_sizes; (void)n_in; (void)out_size;

    unsigned short* hi = (unsigned short*)d_out;     // act bf16 hi plane
    unsigned short* lo = hi + (size_t)NNODES * 128;  // act bf16 lo plane

    hipMemsetAsync(count, 0, (size_t)NNODES * 4, stream);
    k_count  <<<(NEDGES + 8 * 256 - 1) / (8 * 256), 256, 0, stream>>>(ei, count, pos);
    k_bsum   <<<SCAN_NB, 256, 0, stream>>>(count, bsum);
    k_bscan  <<<1, 256, 0, stream>>>(bsum, boff, row_ptr);
    k_rowptr <<<SCAN_NB, 256, 0, stream>>>(count, boff, row_ptr, csr);
    k_scatter<<<(NEDGES + 4 * 256 - 1) / (4 * 256), 256, 0, stream>>>(ei, row_ptr, pos, csr);
    k_split  <<<(NNODES * 128 / 4 + 255) / 256, 256, 0, stream>>>(x, hi, lo);

    const float* W_h = (const float*)d_in[6];
    const float* ash = (const float*)d_in[7];
    const float* adh = (const float*)d_in[8];
    const float* bh  = (const float*)d_in[9];

    struct Layer { const float *W, *as, *ad, *b; };
    Layer L[4] = {
        { (const float*)d_in[2],  (const float*)d_in[3],  (const float*)d_in[4],  (const float*)d_in[5]  },
        { W_h,              ash,        adh,        bh        },
        { W_h + 128 * 128,  ash + 128,  adh + 128,  bh + 128  },
        { (const float*)d_in[10], (const float*)d_in[11], (const float*)d_in[12], (const float*)d_in[13] },
    };

    const int gemm_blocks = (NNODES + 127) / 128;   // 391
    const int agg_blocks  = (NNODES + 3) / 4;
    for (int l = 0; l < 4; l++) {
        k_gemm_mfma<<<gemm_blocks, 256, 0, stream>>>(hi, lo, L[l].W, L[l].as, L[l].ad,
                                                     hh, es, edv);
        if (l < 3) {
            k_aggregate_h<<<agg_blocks, 256, 0, stream>>>(hh, es, edv, row_ptr, csr,
                                                          L[l].b, hi, lo);
        } else {
            k_aggregate_f<<<agg_blocks, 256, 0, stream>>>(hh, es, edv, row_ptr, csr,
                                                          L[l].b, (float*)d_out);
        }
    }
}